// Round 5
// baseline (794.993 us; speedup 1.0000x reference)
//
#include <hip/hip_runtime.h>
#include <hip/hip_bf16.h>
#include <cmath>

#define HH 128
#define WW 128
#define HWSZ (HH*WW)
#define BB 4

typedef __attribute__((ext_vector_type(8))) short short8;
typedef __attribute__((ext_vector_type(16))) float f32x16;

__device__ __forceinline__ ushort bf16_rn(float f) {
    uint u = __builtin_bit_cast(uint, f);
    return (ushort)((u + 0x7fffu + ((u >> 16) & 1u)) >> 16);
}
__device__ __forceinline__ float bf16_f(ushort h) {
    uint u = ((uint)h) << 16;
    return __builtin_bit_cast(float, u);
}
__device__ __forceinline__ uint pack_bf(float v) {
    ushort h = bf16_rn(v);
    ushort l = bf16_rn(v - bf16_f(h));
    return ((uint)h << 16) | (uint)l;
}

// ---------------------------------------------------------------------------
// Weight prep: w fp32 [OC][K] -> whi/wlo bf16 [OCpad][KPAD], zero padded.
// ---------------------------------------------------------------------------
__global__ __launch_bounds__(256) void prep_w_k(const float* __restrict__ w,
                                                ushort* __restrict__ whi,
                                                ushort* __restrict__ wlo,
                                                int OC, int K, int OCpad, int KPAD) {
    int idx = blockIdx.x * 256 + threadIdx.x;
    if (idx >= OCpad * KPAD) return;
    int oc = idx / KPAD, k = idx - oc * KPAD;
    float v = (oc < OC && k < K) ? w[(size_t)oc * K + k] : 0.f;
    ushort h = bf16_rn(v);
    ushort l = bf16_rn(v - bf16_f(h));
    whi[idx] = h;
    wlo[idx] = l;
}

// ---------------------------------------------------------------------------
// Deform weight prep: wdcn [oc][c][k] -> k-major reorder [oc][kidx=k*64+c].
// ---------------------------------------------------------------------------
__global__ __launch_bounds__(256) void prep_wd_k(const float* __restrict__ w,
                                                 ushort* __restrict__ whi,
                                                 ushort* __restrict__ wlo) {
    int idx = blockIdx.x * 256 + threadIdx.x;
    if (idx >= 64 * 576) return;
    int oc = idx / 576, kidx = idx - oc * 576;
    int k = kidx >> 6, c = kidx & 63;
    float v = w[(size_t)oc * 576 + c * 9 + k];
    ushort h = bf16_rn(v);
    ushort l = bf16_rn(v - bf16_f(h));
    whi[idx] = h;
    wlo[idx] = l;
}

// ---------------------------------------------------------------------------
// Input concat+pack: {xfw(64), xcur(64), flow(2), zero(2)} -> packed uint
// planes [b][132][H][W] (hi bf16 <<16 | lo bf16).
// ---------------------------------------------------------------------------
__global__ __launch_bounds__(256) void cvt_in_k(const float* __restrict__ xfw,
                                                const float* __restrict__ xcur,
                                                const float* __restrict__ flow,
                                                uint* __restrict__ concatP) {
    int idx = blockIdx.x * 256 + threadIdx.x;
    if (idx >= BB * 132 * HWSZ) return;
    int b = idx / (132 * HWSZ);
    int rem = idx - b * 132 * HWSZ;
    int c = rem / HWSZ, pix = rem - c * HWSZ;
    float v = 0.f;
    if (c < 64)       v = xfw [((size_t)b * 64 + c)       * HWSZ + pix];
    else if (c < 128) v = xcur[((size_t)b * 64 + c - 64)  * HWSZ + pix];
    else if (c < 130) v = flow[((size_t)b * 2  + c - 128) * HWSZ + pix];
    concatP[idx] = pack_bf(v);
}

// ---------------------------------------------------------------------------
// Pack x into gather-friendly float4: xP[b][dg][pix] = x[b][dg*4 .. dg*4+3][pix]
// ---------------------------------------------------------------------------
__global__ __launch_bounds__(256) void pack_x_k(const float* __restrict__ x,
                                                float4* __restrict__ xP) {
    int idx = blockIdx.x * 256 + threadIdx.x;
    if (idx >= BB * 16 * HWSZ) return;
    int b = idx / (16 * HWSZ);
    int rem = idx - b * 16 * HWSZ;
    int dg = rem / HWSZ, pix = rem - dg * HWSZ;
    const float* src = x + ((size_t)b * 64 + dg * 4) * HWSZ + pix;
    float4 v;
    v.x = src[0];
    v.y = src[HWSZ];
    v.z = src[2 * HWSZ];
    v.w = src[3 * HWSZ];
    xP[idx] = v;
}

// ---------------------------------------------------------------------------
// Implicit-GEMM MFMA conv3x3, split-bf16x2, packed-uint activations.
// 512 threads = 8 waves (2M x 4N). Block tile: NG*64 oc x 128 px (one row).
// A (weights): direct per-lane global loads (L2/L1-hot) -- no weight LDS.
// B (im2col): LDS ping-pong double-buffer, 1 barrier/chunk, T14 prefetch
//   (FETCH next chunk into regs before MFMA phase, WRITE after).
// MODE 1: lrelu, packed-uint output.   MODE 2: conv3 epilogue, fp32 output.
// ---------------------------------------------------------------------------
template<int NG, int IC, int KPAD, int MODE>
__global__ __launch_bounds__(512, 4) void conv_v4(
    const uint* __restrict__ inP,
    const ushort* __restrict__ whi, const ushort* __restrict__ wlo,
    const float* __restrict__ bias, void* __restrict__ outPtr,
    const float* __restrict__ flow)
{
    constexpr int NCHUNK = KPAD / 32;
    constexpr int LDK = 40;

    __shared__ ushort iHi[2][128 * LDK], iLo[2][128 * LDK];

    const int tid = threadIdx.x;
    const int row = blockIdx.x;
    const int b = row >> 7, y = row & 127;
    const int o0 = blockIdx.y * (NG * 64);

    const int wave = tid >> 6, lane = tid & 63;
    const int wm = wave >> 2, wn = wave & 3;     // 2 x 4 wave grid
    const int l31 = lane & 31, lhi = lane >> 5;
    const int spx = tid & 127;                    // staged px
    const int sko = __builtin_amdgcn_readfirstlane(tid >> 7);  // k-octet 0..3

    f32x16 acc[NG] = {};
    uint pb[8];

    // fetch one chunk's im2col slice (8 k for this thread's px) into regs
    auto FETCH = [&](int kc) {
        #pragma unroll
        for (int j = 0; j < 8; ++j) {
            const int k  = kc * 32 + sko * 8 + j;   // scalar
            const int ic = k / 9;
            const int kk = k - ic * 9;
            const int ky = kk / 3;
            const int kx = kk - ky * 3;
            const int gy = y + ky - 1;              // scalar
            const uint* prow = inP + ((size_t)b * IC + ic) * HWSZ + gy * WW;
            const int gx = spx + kx - 1;            // vector
            uint u = 0;
            if ((unsigned)gy < (unsigned)HH && (unsigned)gx < (unsigned)WW)
                u = prow[gx];
            pb[j] = u;
        }
    };
    auto WRITE = [&](int buf) {
        short8 ph, pl;
        #pragma unroll
        for (int j = 0; j < 8; ++j) {
            ph[j] = (short)(pb[j] >> 16);
            pl[j] = (short)(pb[j] & 0xffffu);
        }
        *(short8*)&iHi[buf][spx * LDK + sko * 8] = ph;
        *(short8*)&iLo[buf][spx * LDK + sko * 8] = pl;
    };

    FETCH(0);
    WRITE(0);

    for (int kc = 0; kc < NCHUNK; ++kc) {
        __syncthreads();                       // buf[kc&1] visible to all
        const int cur = kc & 1;

        // issue A-fragment loads for this chunk (global, L2-hot)
        short8 afh[2][NG], afl[2][NG];
        #pragma unroll
        for (int ks = 0; ks < 2; ++ks) {
            const int koff = ks * 16 + lhi * 8;
            #pragma unroll
            for (int mg = 0; mg < NG; ++mg) {
                const size_t ga = (size_t)(o0 + wm * (NG * 32) + mg * 32 + l31) * KPAD
                                + kc * 32 + koff;
                afh[ks][mg] = *(const short8*)&whi[ga];
                afl[ks][mg] = *(const short8*)&wlo[ga];
            }
        }
        // issue B prefetch for next chunk (lands during MFMA phase)
        if (kc + 1 < NCHUNK) FETCH(kc + 1);

        // MFMA phase: B from LDS buf[cur], A from the just-issued globals
        #pragma unroll
        for (int ks = 0; ks < 2; ++ks) {
            const int koff = ks * 16 + lhi * 8;
            const int ib = (wn * 32 + l31) * LDK + koff;
            const short8 bh = *(const short8*)&iHi[cur][ib];
            const short8 bl = *(const short8*)&iLo[cur][ib];
            #pragma unroll
            for (int mg = 0; mg < NG; ++mg) {
                acc[mg] = __builtin_amdgcn_mfma_f32_32x32x16_bf16(afh[ks][mg], bh, acc[mg], 0, 0, 0);
                acc[mg] = __builtin_amdgcn_mfma_f32_32x32x16_bf16(afh[ks][mg], bl, acc[mg], 0, 0, 0);
                acc[mg] = __builtin_amdgcn_mfma_f32_32x32x16_bf16(afl[ks][mg], bh, acc[mg], 0, 0, 0);
            }
        }

        // write prefetched B into the other buffer (after MFMA = T14)
        if (kc + 1 < NCHUNK) WRITE(1 - cur);
    }

    // ---- epilogue ----
    const int px = wn * 32 + l31;
    if (MODE == 1) {
        uint* outP = (uint*)outPtr;
        #pragma unroll
        for (int r = 0; r < 16; ++r) {
            const int oc = wm * 32 + (r & 3) + 8 * (r >> 2) + 4 * lhi;
            float v = acc[0][r] + bias[oc];
            v = v >= 0.f ? v : 0.1f * v;
            outP[((size_t)b * 64 + oc) * HWSZ + y * WW + px] = pack_bf(v);
        }
    } else {
        float* outF = (float*)outPtr;
        #pragma unroll
        for (int mg = 0; mg < NG; ++mg) {
            #pragma unroll
            for (int r = 0; r < 16; ++r) {
                const int oc = o0 + wm * (NG * 32) + mg * 32
                             + (r & 3) + 8 * (r >> 2) + 4 * lhi;
                if (oc < 432) {
                    float v = acc[mg][r] + bias[oc];
                    float res;
                    if (oc < 288) {
                        const float fl = flow[(((size_t)b * 2 + ((oc & 1) ? 0 : 1)) * HH + y) * WW + px];
                        res = 10.f * tanhf(v) + fl;
                    } else {
                        res = 1.f / (1.f + expf(-v));
                    }
                    outF[((size_t)b * 432 + oc) * HWSZ + y * WW + px] = res;
                }
            }
        }
    }
}

// ---------------------------------------------------------------------------
// MFMA deformable conv, zero-LDS / zero-barrier. 256 threads = 4 waves (2x2).
// Block: 64 oc x 64 px. K k-major (kidx = k9*64 + dg*4 + cc), 18 half-chunks.
// Each lane bilinear-samples ITS OWN B-fragment (2 dgs x 4 ch at its pixel)
// straight into registers; A-fragments loaded direct from global (L2-hot).
// ---------------------------------------------------------------------------
__global__ __launch_bounds__(256, 4) void deform_v3(
    const float4* __restrict__ xP, const float* __restrict__ offm,
    const ushort* __restrict__ wdh, const ushort* __restrict__ wdl,
    const float* __restrict__ bias, float* __restrict__ outp)
{
    const int tid = threadIdx.x;
    const int x0  = blockIdx.x * 64;
    const int y   = blockIdx.y;
    const int b   = blockIdx.z;

    const int wave = tid >> 6, lane = tid & 63;
    const int wm = wave >> 1, wn = wave & 1;
    const int l31 = lane & 31, lhi = lane >> 5;

    const int xp  = x0 + wn * 32 + l31;      // this lane's pixel (B column)
    const int pix = y * WW + xp;
    const float* offb = offm + (size_t)b * 432 * HWSZ;
    const float fy = (float)y, fx = (float)xp;

    f32x16 acc = {};

    for (int k9 = 0; k9 < 9; ++k9) {
        const float kyf = (float)(k9 / 3 - 1);
        const float kxf = (float)(k9 % 3 - 1);
        #pragma unroll
        for (int half = 0; half < 2; ++half) {
            // A-fragments for both ks (issue early, use after sampling)
            short8 ah0, al0, ah1, al1;
            {
                const ushort* wr = wdh + (size_t)(wm * 32 + l31) * 576 + k9 * 64 + half * 32 + lhi * 8;
                const ushort* wl = wdl + (size_t)(wm * 32 + l31) * 576 + k9 * 64 + half * 32 + lhi * 8;
                ah0 = *(const short8*)&wr[0];
                ah1 = *(const short8*)&wr[16];
                al0 = *(const short8*)&wl[0];
                al1 = *(const short8*)&wl[16];
            }
            #pragma unroll
            for (int ks = 0; ks < 2; ++ks) {
                // build this lane's B-fragment: dgs {half*8+ks*4+lhi*2, +1}
                short8 bf;
                #pragma unroll
                for (int d2 = 0; d2 < 2; ++d2) {
                    const int dg = half * 8 + ks * 4 + lhi * 2 + d2;
                    const float dy = offb[(size_t)(dg * 18 + k9 * 2)     * HWSZ + pix];
                    const float dx = offb[(size_t)(dg * 18 + k9 * 2 + 1) * HWSZ + pix];
                    const float mk = offb[(size_t)(288 + dg * 9 + k9)    * HWSZ + pix];
                    const float py = dy + kyf + fy;
                    const float px = dx + kxf + fx;
                    const float y0f = floorf(py), x0f = floorf(px);
                    const float ly = py - y0f, lx = px - x0f;
                    const int yi = (int)y0f, xi = (int)x0f;
                    const float w00 = (1.f - ly) * (1.f - lx), w01 = (1.f - ly) * lx;
                    const float w10 = ly * (1.f - lx),         w11 = ly * lx;
                    const bool vy0 = (unsigned)yi < (unsigned)HH, vy1 = (unsigned)(yi + 1) < (unsigned)HH;
                    const bool vx0 = (unsigned)xi < (unsigned)WW, vx1 = (unsigned)(xi + 1) < (unsigned)WW;
                    const float f00 = (vy0 && vx0) ? w00 * mk : 0.f;
                    const float f01 = (vy0 && vx1) ? w01 * mk : 0.f;
                    const float f10 = (vy1 && vx0) ? w10 * mk : 0.f;
                    const float f11 = (vy1 && vx1) ? w11 * mk : 0.f;
                    const int cy0 = min(max(yi, 0), HH - 1), cy1 = min(max(yi + 1, 0), HH - 1);
                    const int cx0 = min(max(xi, 0), WW - 1), cx1 = min(max(xi + 1, 0), WW - 1);
                    const float4* xg = xP + (size_t)(b * 16 + dg) * HWSZ;
                    const float4 c00 = xg[cy0 * WW + cx0], c01 = xg[cy0 * WW + cx1];
                    const float4 c10 = xg[cy1 * WW + cx0], c11 = xg[cy1 * WW + cx1];
                    bf[d2 * 4 + 0] = (short)bf16_rn(f00 * c00.x + f01 * c01.x + f10 * c10.x + f11 * c11.x);
                    bf[d2 * 4 + 1] = (short)bf16_rn(f00 * c00.y + f01 * c01.y + f10 * c10.y + f11 * c11.y);
                    bf[d2 * 4 + 2] = (short)bf16_rn(f00 * c00.z + f01 * c01.z + f10 * c10.z + f11 * c11.z);
                    bf[d2 * 4 + 3] = (short)bf16_rn(f00 * c00.w + f01 * c01.w + f10 * c10.w + f11 * c11.w);
                }
                if (ks == 0) {
                    acc = __builtin_amdgcn_mfma_f32_32x32x16_bf16(ah0, bf, acc, 0, 0, 0);
                    acc = __builtin_amdgcn_mfma_f32_32x32x16_bf16(al0, bf, acc, 0, 0, 0);
                } else {
                    acc = __builtin_amdgcn_mfma_f32_32x32x16_bf16(ah1, bf, acc, 0, 0, 0);
                    acc = __builtin_amdgcn_mfma_f32_32x32x16_bf16(al1, bf, acc, 0, 0, 0);
                }
            }
        }
    }

    // ---- epilogue ----
    #pragma unroll
    for (int r = 0; r < 16; ++r) {
        const int oc = wm * 32 + (r & 3) + 8 * (r >> 2) + 4 * lhi;
        outp[(((size_t)b * 64 + oc) * HH + y) * WW + xp] = acc[r] + bias[oc];
    }
}

// ---------------------------------------------------------------------------
extern "C" void kernel_launch(void* const* d_in, const int* in_sizes, int n_in,
                              void* d_out, int out_size, void* d_ws, size_t ws_size,
                              hipStream_t stream) {
    const float* x    = (const float*)d_in[0];
    const float* xfw  = (const float*)d_in[1];
    const float* xcur = (const float*)d_in[2];
    const float* flow = (const float*)d_in[3];
    const float* w0   = (const float*)d_in[4];
    const float* b0   = (const float*)d_in[5];
    const float* w1   = (const float*)d_in[6];
    const float* b1   = (const float*)d_in[7];
    const float* w2   = (const float*)d_in[8];
    const float* b2   = (const float*)d_in[9];
    const float* w3   = (const float*)d_in[10];
    const float* b3   = (const float*)d_in[11];
    const float* wdcn = (const float*)d_in[12];
    const float* bdcn = (const float*)d_in[13];
    float* out = (float*)d_out;

    // workspace layout (aliased; stream order makes it safe):
    //   [0, 113.2MB)  offm fp32   (concatP aliases its head, dead before conv3)
    //   [+16.8MB)     h0P packed  (conv2 output reuses = h2P)
    //   [+16.8MB)     h1P packed  (xP float4 aliases after conv2 reads h1P)
    //   [+...]        weight buffers
    float* offm   = (float*)d_ws;
    uint* concatP = (uint*)d_ws;
    uint* h0P     = (uint*)((char*)d_ws + (size_t)BB * 432 * HWSZ * 4);
    uint* h1P     = h0P + (size_t)BB * 64 * HWSZ;
    float4* xP    = (float4*)h1P;
    ushort* wp    = (ushort*)(h1P + (size_t)BB * 64 * HWSZ);
    ushort* wdh  = wp;                 ushort* wdl  = wdh + 64 * 576;
    ushort* w0hi = wdl + 64 * 576;     ushort* w0lo = w0hi + 64 * 1184;
    ushort* w1hi = w0lo + 64 * 1184;   ushort* w1lo = w1hi + 64 * 576;
    ushort* w2hi = w1lo + 64 * 576;    ushort* w2lo = w2hi + 64 * 576;
    ushort* w3hi = w2lo + 64 * 576;    ushort* w3lo = w3hi + (size_t)512 * 576;
    uint* h2P = h0P;   // conv2 output reuses h0P

    prep_w_k<<<dim3((64 * 1184 + 255) / 256), dim3(256), 0, stream>>>(w0, w0hi, w0lo, 64, 1170, 64, 1184);
    prep_w_k<<<dim3((64 * 576 + 255) / 256),  dim3(256), 0, stream>>>(w1, w1hi, w1lo, 64, 576, 64, 576);
    prep_w_k<<<dim3((64 * 576 + 255) / 256),  dim3(256), 0, stream>>>(w2, w2hi, w2lo, 64, 576, 64, 576);
    prep_w_k<<<dim3((512 * 576 + 255) / 256), dim3(256), 0, stream>>>(w3, w3hi, w3lo, 432, 576, 512, 576);
    prep_wd_k<<<dim3((64 * 576 + 255) / 256), dim3(256), 0, stream>>>(wdcn, wdh, wdl);
    cvt_in_k<<<dim3((BB * 132 * HWSZ + 255) / 256), dim3(256), 0, stream>>>(xfw, xcur, flow, concatP);

    conv_v4<1, 132, 1184, 1><<<dim3(BB * HH, 1), dim3(512), 0, stream>>>(concatP, w0hi, w0lo, b0, h0P, nullptr);
    conv_v4<1, 64, 576, 1><<<dim3(BB * HH, 1), dim3(512), 0, stream>>>(h0P, w1hi, w1lo, b1, h1P, nullptr);
    conv_v4<1, 64, 576, 1><<<dim3(BB * HH, 1), dim3(512), 0, stream>>>(h1P, w2hi, w2lo, b2, h2P, nullptr);
    pack_x_k<<<dim3((BB * 16 * HWSZ + 255) / 256), dim3(256), 0, stream>>>(x, xP);
    conv_v4<2, 64, 576, 2><<<dim3(BB * HH, 4), dim3(512), 0, stream>>>(h2P, w3hi, w3lo, b3, offm, flow);

    deform_v3<<<dim3(2, 128, BB), dim3(256), 0, stream>>>(xP, offm, wdh, wdl, bdcn, out);
}

// Round 6
// 649.628 us; speedup vs baseline: 1.2238x; 1.2238x over previous
//
#include <hip/hip_runtime.h>
#include <hip/hip_bf16.h>
#include <cmath>

#define HH 128
#define WW 128
#define HWSZ (HH*WW)
#define BB 4

typedef __attribute__((ext_vector_type(8))) short short8;
typedef __attribute__((ext_vector_type(16))) float f32x16;

__device__ __forceinline__ ushort bf16_rn(float f) {
    uint u = __builtin_bit_cast(uint, f);
    return (ushort)((u + 0x7fffu + ((u >> 16) & 1u)) >> 16);
}
__device__ __forceinline__ float bf16_f(ushort h) {
    uint u = ((uint)h) << 16;
    return __builtin_bit_cast(float, u);
}
__device__ __forceinline__ uint pack_bf(float v) {
    ushort h = bf16_rn(v);
    ushort l = bf16_rn(v - bf16_f(h));
    return ((uint)h << 16) | (uint)l;
}

// ---------------------------------------------------------------------------
// Weight prep -> FRAGMENT-READY layout:
//   dst = kc*32*OCpad + ks*16*OCpad + oc*16 + lhi*8 + j
// (k = kc*32 + ks*16 + lhi*8 + j). A wave's fragment load (32 oc x 2 lhi) is
// a contiguous 1KB block -> fully coalesced global_load_dwordx4.
// ---------------------------------------------------------------------------
__global__ __launch_bounds__(256) void prep_wf_k(const float* __restrict__ w,
                                                 ushort* __restrict__ whiF,
                                                 ushort* __restrict__ wloF,
                                                 int OC, int K, int OCpad, int KPAD) {
    int idx = blockIdx.x * 256 + threadIdx.x;
    if (idx >= OCpad * KPAD) return;
    int oc = idx / KPAD, k = idx - oc * KPAD;
    float v = (oc < OC && k < K) ? w[(size_t)oc * K + k] : 0.f;
    ushort h = bf16_rn(v);
    ushort l = bf16_rn(v - bf16_f(h));
    const int kc = k >> 5, r = k & 31;
    const int ks = r >> 4, lhi = (r >> 3) & 1, j = r & 7;
    const size_t dst = (size_t)kc * 32 * OCpad + ks * 16 * OCpad + oc * 16 + lhi * 8 + j;
    whiF[dst] = h;
    wloF[dst] = l;
}

// ---------------------------------------------------------------------------
// Deform weight prep -> fragment-ready:
//   k-major kidx = k9*64 + c;  c = half*32 + ks*16 + lhi*8 + j
//   dst = ((k9*2+half)*2+ks)*1024 + oc*16 + lhi*8 + j
// ---------------------------------------------------------------------------
__global__ __launch_bounds__(256) void prep_wdf_k(const float* __restrict__ w,
                                                  ushort* __restrict__ whiF,
                                                  ushort* __restrict__ wloF) {
    int idx = blockIdx.x * 256 + threadIdx.x;
    if (idx >= 64 * 576) return;
    int oc = idx / 576, rem = idx - oc * 576;
    int k9 = rem / 64, c = rem & 63;
    float v = w[(size_t)oc * 576 + c * 9 + k9];
    ushort h = bf16_rn(v);
    ushort l = bf16_rn(v - bf16_f(h));
    const int half = c >> 5, r = c & 31;
    const int ks = r >> 4, lhi = (r >> 3) & 1, j = r & 7;
    const size_t dst = (size_t)((k9 * 2 + half) * 2 + ks) * 1024 + oc * 16 + lhi * 8 + j;
    whiF[dst] = h;
    wloF[dst] = l;
}

// ---------------------------------------------------------------------------
// Input concat+pack: {xfw(64), xcur(64), flow(2), zero(2)} -> packed uint
// planes [b][132][H][W] (hi bf16 <<16 | lo bf16).
// ---------------------------------------------------------------------------
__global__ __launch_bounds__(256) void cvt_in_k(const float* __restrict__ xfw,
                                                const float* __restrict__ xcur,
                                                const float* __restrict__ flow,
                                                uint* __restrict__ concatP) {
    int idx = blockIdx.x * 256 + threadIdx.x;
    if (idx >= BB * 132 * HWSZ) return;
    int b = idx / (132 * HWSZ);
    int rem = idx - b * 132 * HWSZ;
    int c = rem / HWSZ, pix = rem - c * HWSZ;
    float v = 0.f;
    if (c < 64)       v = xfw [((size_t)b * 64 + c)       * HWSZ + pix];
    else if (c < 128) v = xcur[((size_t)b * 64 + c - 64)  * HWSZ + pix];
    else if (c < 130) v = flow[((size_t)b * 2  + c - 128) * HWSZ + pix];
    concatP[idx] = pack_bf(v);
}

// ---------------------------------------------------------------------------
// Pack x into gather-friendly float4: xP[b][dg][pix] = x[b][dg*4..dg*4+3][pix]
// ---------------------------------------------------------------------------
__global__ __launch_bounds__(256) void pack_x_k(const float* __restrict__ x,
                                                float4* __restrict__ xP) {
    int idx = blockIdx.x * 256 + threadIdx.x;
    if (idx >= BB * 16 * HWSZ) return;
    int b = idx / (16 * HWSZ);
    int rem = idx - b * 16 * HWSZ;
    int dg = rem / HWSZ, pix = rem - dg * HWSZ;
    const float* src = x + ((size_t)b * 64 + dg * 4) * HWSZ + pix;
    float4 v;
    v.x = src[0];
    v.y = src[HWSZ];
    v.z = src[2 * HWSZ];
    v.w = src[3 * HWSZ];
    xP[idx] = v;
}

// ---------------------------------------------------------------------------
// Implicit-GEMM MFMA conv3x3, split-bf16x2, packed-uint activations.
// 512 threads = 8 waves (2M x 4N). Block tile: NG*64 oc x 128 px (one row).
// A: fragment-ready coalesced global loads (L1/L2-hot, no LDS).
// B: LDS ping-pong double-buffer, 1 barrier/chunk, issue-early/write-late.
// MODE 1: lrelu, packed-uint output.   MODE 2: conv3 epilogue, fp32 output.
// ---------------------------------------------------------------------------
template<int NG, int IC, int KPAD, int OCPAD, int MODE>
__global__ __launch_bounds__(512, 4) void conv_v6(
    const uint* __restrict__ inP,
    const ushort* __restrict__ whiF, const ushort* __restrict__ wloF,
    const float* __restrict__ bias, void* __restrict__ outPtr,
    const float* __restrict__ flow)
{
    constexpr int NCHUNK = KPAD / 32;
    constexpr int LDK = 40;

    __shared__ ushort iHi[2][128 * LDK], iLo[2][128 * LDK];

    const int tid = threadIdx.x;
    const int row = blockIdx.x;
    const int b = row >> 7, y = row & 127;
    const int o0 = blockIdx.y * (NG * 64);

    const int wave = tid >> 6, lane = tid & 63;
    const int wm = wave >> 2, wn = wave & 3;     // 2 x 4 wave grid
    const int l31 = lane & 31, lhi = lane >> 5;
    const int spx = tid & 127;                    // staged px
    const int sko = __builtin_amdgcn_readfirstlane(tid >> 7);  // k-octet 0..3

    f32x16 acc[NG] = {};
    uint pb[8];

    auto FETCH = [&](int kc) {
        #pragma unroll
        for (int j = 0; j < 8; ++j) {
            const int k  = kc * 32 + sko * 8 + j;   // scalar
            const int ic = k / 9;
            const int kk = k - ic * 9;
            const int ky = kk / 3;
            const int kx = kk - ky * 3;
            const int gy = y + ky - 1;              // scalar
            const uint* prow = inP + ((size_t)b * IC + ic) * HWSZ + gy * WW;
            const int gx = spx + kx - 1;            // vector
            uint u = 0;
            if ((unsigned)gy < (unsigned)HH && (unsigned)gx < (unsigned)WW)
                u = prow[gx];
            pb[j] = u;
        }
    };
    auto WRITE = [&](int buf) {
        short8 ph, pl;
        #pragma unroll
        for (int j = 0; j < 8; ++j) {
            ph[j] = (short)(pb[j] >> 16);
            pl[j] = (short)(pb[j] & 0xffffu);
        }
        *(short8*)&iHi[buf][spx * LDK + sko * 8] = ph;
        *(short8*)&iLo[buf][spx * LDK + sko * 8] = pl;
    };

    FETCH(0);
    WRITE(0);

    for (int kc = 0; kc < NCHUNK; ++kc) {
        __syncthreads();                       // buf[kc&1] visible to all
        const int cur = kc & 1;

        // B prefetch for next chunk (longest latency -> issue first)
        if (kc + 1 < NCHUNK) FETCH(kc + 1);

        // A fragments: contiguous 1KB per wave per (ks,mg) -- coalesced
        short8 afh[2][NG], afl[2][NG];
        #pragma unroll
        for (int ks = 0; ks < 2; ++ks) {
            #pragma unroll
            for (int mg = 0; mg < NG; ++mg) {
                const size_t ga = (size_t)kc * 32 * OCPAD + (size_t)ks * 16 * OCPAD
                                + (o0 + wm * (NG * 32) + mg * 32 + l31) * 16 + lhi * 8;
                afh[ks][mg] = *(const short8*)&whiF[ga];
                afl[ks][mg] = *(const short8*)&wloF[ga];
            }
        }

        // MFMA phase: B from LDS buf[cur]
        #pragma unroll
        for (int ks = 0; ks < 2; ++ks) {
            const int koff = ks * 16 + lhi * 8;
            const int ib = (wn * 32 + l31) * LDK + koff;
            const short8 bh = *(const short8*)&iHi[cur][ib];
            const short8 bl = *(const short8*)&iLo[cur][ib];
            #pragma unroll
            for (int mg = 0; mg < NG; ++mg) {
                acc[mg] = __builtin_amdgcn_mfma_f32_32x32x16_bf16(afh[ks][mg], bh, acc[mg], 0, 0, 0);
                acc[mg] = __builtin_amdgcn_mfma_f32_32x32x16_bf16(afh[ks][mg], bl, acc[mg], 0, 0, 0);
                acc[mg] = __builtin_amdgcn_mfma_f32_32x32x16_bf16(afl[ks][mg], bh, acc[mg], 0, 0, 0);
            }
        }

        // write prefetched B into the other buffer (after MFMA = T14)
        if (kc + 1 < NCHUNK) WRITE(1 - cur);
    }

    // ---- epilogue ----
    const int px = wn * 32 + l31;
    if (MODE == 1) {
        uint* outP = (uint*)outPtr;
        #pragma unroll
        for (int r = 0; r < 16; ++r) {
            const int oc = wm * 32 + (r & 3) + 8 * (r >> 2) + 4 * lhi;
            float v = acc[0][r] + bias[oc];
            v = v >= 0.f ? v : 0.1f * v;
            outP[((size_t)b * 64 + oc) * HWSZ + y * WW + px] = pack_bf(v);
        }
    } else {
        float* outF = (float*)outPtr;
        #pragma unroll
        for (int mg = 0; mg < NG; ++mg) {
            #pragma unroll
            for (int r = 0; r < 16; ++r) {
                const int oc = o0 + wm * (NG * 32) + mg * 32
                             + (r & 3) + 8 * (r >> 2) + 4 * lhi;
                if (oc < 432) {
                    float v = acc[mg][r] + bias[oc];
                    float res;
                    if (oc < 288) {
                        const float fl = flow[(((size_t)b * 2 + ((oc & 1) ? 0 : 1)) * HH + y) * WW + px];
                        res = 10.f * tanhf(v) + fl;
                    } else {
                        res = 1.f / (1.f + expf(-v));
                    }
                    outF[((size_t)b * 432 + oc) * HWSZ + y * WW + px] = res;
                }
            }
        }
    }
}

// ---------------------------------------------------------------------------
// MFMA deformable conv, zero-LDS / zero-barrier. 256 threads = 4 waves (2x2).
// Block: 64 oc x 64 px. K k-major (kidx = k9*64 + dg*4 + cc), 18 half-chunks.
// Each lane bilinear-samples ITS OWN B-fragment (2 dgs x 4 ch at its pixel)
// straight into registers; A-fragments fragment-ready coalesced from global.
// ---------------------------------------------------------------------------
__global__ __launch_bounds__(256, 4) void deform_v4(
    const float4* __restrict__ xP, const float* __restrict__ offm,
    const ushort* __restrict__ wdfh, const ushort* __restrict__ wdfl,
    const float* __restrict__ bias, float* __restrict__ outp)
{
    const int tid = threadIdx.x;
    const int x0  = blockIdx.x * 64;
    const int y   = blockIdx.y;
    const int b   = blockIdx.z;

    const int wave = tid >> 6, lane = tid & 63;
    const int wm = wave >> 1, wn = wave & 1;
    const int l31 = lane & 31, lhi = lane >> 5;

    const int xp  = x0 + wn * 32 + l31;      // this lane's pixel (B column)
    const int pix = y * WW + xp;
    const float* offb = offm + (size_t)b * 432 * HWSZ;
    const float fy = (float)y, fx = (float)xp;

    f32x16 acc = {};

    for (int k9 = 0; k9 < 9; ++k9) {
        const float kyf = (float)(k9 / 3 - 1);
        const float kxf = (float)(k9 % 3 - 1);
        #pragma unroll
        for (int half = 0; half < 2; ++half) {
            // fragment-ready A: contiguous 1KB per wave per ks
            const size_t abase = (size_t)((k9 * 2 + half) * 2) * 1024
                               + (wm * 32 + l31) * 16 + lhi * 8;
            const short8 ah0 = *(const short8*)&wdfh[abase];
            const short8 al0 = *(const short8*)&wdfl[abase];
            const short8 ah1 = *(const short8*)&wdfh[abase + 1024];
            const short8 al1 = *(const short8*)&wdfl[abase + 1024];
            #pragma unroll
            for (int ks = 0; ks < 2; ++ks) {
                // build this lane's B-fragment: dgs {half*8+ks*4+lhi*2, +1}
                short8 bf;
                #pragma unroll
                for (int d2 = 0; d2 < 2; ++d2) {
                    const int dg = half * 8 + ks * 4 + lhi * 2 + d2;
                    const float dy = offb[(size_t)(dg * 18 + k9 * 2)     * HWSZ + pix];
                    const float dx = offb[(size_t)(dg * 18 + k9 * 2 + 1) * HWSZ + pix];
                    const float mk = offb[(size_t)(288 + dg * 9 + k9)    * HWSZ + pix];
                    const float py = dy + kyf + fy;
                    const float px = dx + kxf + fx;
                    const float y0f = floorf(py), x0f = floorf(px);
                    const float ly = py - y0f, lx = px - x0f;
                    const int yi = (int)y0f, xi = (int)x0f;
                    const float w00 = (1.f - ly) * (1.f - lx), w01 = (1.f - ly) * lx;
                    const float w10 = ly * (1.f - lx),         w11 = ly * lx;
                    const bool vy0 = (unsigned)yi < (unsigned)HH, vy1 = (unsigned)(yi + 1) < (unsigned)HH;
                    const bool vx0 = (unsigned)xi < (unsigned)WW, vx1 = (unsigned)(xi + 1) < (unsigned)WW;
                    const float f00 = (vy0 && vx0) ? w00 * mk : 0.f;
                    const float f01 = (vy0 && vx1) ? w01 * mk : 0.f;
                    const float f10 = (vy1 && vx0) ? w10 * mk : 0.f;
                    const float f11 = (vy1 && vx1) ? w11 * mk : 0.f;
                    const int cy0 = min(max(yi, 0), HH - 1), cy1 = min(max(yi + 1, 0), HH - 1);
                    const int cx0 = min(max(xi, 0), WW - 1), cx1 = min(max(xi + 1, 0), WW - 1);
                    const float4* xg = xP + (size_t)(b * 16 + dg) * HWSZ;
                    const float4 c00 = xg[cy0 * WW + cx0], c01 = xg[cy0 * WW + cx1];
                    const float4 c10 = xg[cy1 * WW + cx0], c11 = xg[cy1 * WW + cx1];
                    bf[d2 * 4 + 0] = (short)bf16_rn(f00 * c00.x + f01 * c01.x + f10 * c10.x + f11 * c11.x);
                    bf[d2 * 4 + 1] = (short)bf16_rn(f00 * c00.y + f01 * c01.y + f10 * c10.y + f11 * c11.y);
                    bf[d2 * 4 + 2] = (short)bf16_rn(f00 * c00.z + f01 * c01.z + f10 * c10.z + f11 * c11.z);
                    bf[d2 * 4 + 3] = (short)bf16_rn(f00 * c00.w + f01 * c01.w + f10 * c10.w + f11 * c11.w);
                }
                if (ks == 0) {
                    acc = __builtin_amdgcn_mfma_f32_32x32x16_bf16(ah0, bf, acc, 0, 0, 0);
                    acc = __builtin_amdgcn_mfma_f32_32x32x16_bf16(al0, bf, acc, 0, 0, 0);
                } else {
                    acc = __builtin_amdgcn_mfma_f32_32x32x16_bf16(ah1, bf, acc, 0, 0, 0);
                    acc = __builtin_amdgcn_mfma_f32_32x32x16_bf16(al1, bf, acc, 0, 0, 0);
                }
            }
        }
    }

    // ---- epilogue ----
    #pragma unroll
    for (int r = 0; r < 16; ++r) {
        const int oc = wm * 32 + (r & 3) + 8 * (r >> 2) + 4 * lhi;
        outp[(((size_t)b * 64 + oc) * HH + y) * WW + xp] = acc[r] + bias[oc];
    }
}

// ---------------------------------------------------------------------------
extern "C" void kernel_launch(void* const* d_in, const int* in_sizes, int n_in,
                              void* d_out, int out_size, void* d_ws, size_t ws_size,
                              hipStream_t stream) {
    const float* x    = (const float*)d_in[0];
    const float* xfw  = (const float*)d_in[1];
    const float* xcur = (const float*)d_in[2];
    const float* flow = (const float*)d_in[3];
    const float* w0   = (const float*)d_in[4];
    const float* b0   = (const float*)d_in[5];
    const float* w1   = (const float*)d_in[6];
    const float* b1   = (const float*)d_in[7];
    const float* w2   = (const float*)d_in[8];
    const float* b2   = (const float*)d_in[9];
    const float* w3   = (const float*)d_in[10];
    const float* b3   = (const float*)d_in[11];
    const float* wdcn = (const float*)d_in[12];
    const float* bdcn = (const float*)d_in[13];
    float* out = (float*)d_out;

    // workspace layout (aliased; stream order makes it safe):
    //   [0, 113.2MB)  offm fp32   (concatP aliases its head, dead before conv3)
    //   [+16.8MB)     h0P packed  (conv2 output reuses = h2P)
    //   [+16.8MB)     h1P packed  (xP float4 aliases after conv2 reads h1P)
    //   [+...]        fragment-ready weight buffers
    float* offm   = (float*)d_ws;
    uint* concatP = (uint*)d_ws;
    uint* h0P     = (uint*)((char*)d_ws + (size_t)BB * 432 * HWSZ * 4);
    uint* h1P     = h0P + (size_t)BB * 64 * HWSZ;
    float4* xP    = (float4*)h1P;
    ushort* wp    = (ushort*)(h1P + (size_t)BB * 64 * HWSZ);
    ushort* wdh  = wp;                 ushort* wdl  = wdh + 64 * 576;
    ushort* w0hi = wdl + 64 * 576;     ushort* w0lo = w0hi + 64 * 1184;
    ushort* w1hi = w0lo + 64 * 1184;   ushort* w1lo = w1hi + 64 * 576;
    ushort* w2hi = w1lo + 64 * 576;    ushort* w2lo = w2hi + 64 * 576;
    ushort* w3hi = w2lo + 64 * 576;    ushort* w3lo = w3hi + (size_t)512 * 576;
    uint* h2P = h0P;   // conv2 output reuses h0P

    prep_wf_k<<<dim3((64 * 1184 + 255) / 256), dim3(256), 0, stream>>>(w0, w0hi, w0lo, 64, 1170, 64, 1184);
    prep_wf_k<<<dim3((64 * 576 + 255) / 256),  dim3(256), 0, stream>>>(w1, w1hi, w1lo, 64, 576, 64, 576);
    prep_wf_k<<<dim3((64 * 576 + 255) / 256),  dim3(256), 0, stream>>>(w2, w2hi, w2lo, 64, 576, 64, 576);
    prep_wf_k<<<dim3((512 * 576 + 255) / 256), dim3(256), 0, stream>>>(w3, w3hi, w3lo, 432, 576, 512, 576);
    prep_wdf_k<<<dim3((64 * 576 + 255) / 256), dim3(256), 0, stream>>>(wdcn, wdh, wdl);
    cvt_in_k<<<dim3((BB * 132 * HWSZ + 255) / 256), dim3(256), 0, stream>>>(xfw, xcur, flow, concatP);

    conv_v6<1, 132, 1184, 64, 1><<<dim3(BB * HH, 1), dim3(512), 0, stream>>>(concatP, w0hi, w0lo, b0, h0P, nullptr);
    conv_v6<1, 64, 576, 64, 1><<<dim3(BB * HH, 1), dim3(512), 0, stream>>>(h0P, w1hi, w1lo, b1, h1P, nullptr);
    conv_v6<1, 64, 576, 64, 1><<<dim3(BB * HH, 1), dim3(512), 0, stream>>>(h1P, w2hi, w2lo, b2, h2P, nullptr);
    pack_x_k<<<dim3((BB * 16 * HWSZ + 255) / 256), dim3(256), 0, stream>>>(x, xP);
    conv_v6<2, 64, 576, 512, 2><<<dim3(BB * HH, 4), dim3(512), 0, stream>>>(h2P, w3hi, w3lo, b3, offm, flow);

    deform_v4<<<dim3(2, 128, BB), dim3(256), 0, stream>>>(xP, offm, wdh, wdl, bdcn, out);
}

// Round 7
// 593.503 us; speedup vs baseline: 1.3395x; 1.0946x over previous
//
#include <hip/hip_runtime.h>
#include <hip/hip_bf16.h>
#include <cmath>

#define HH 128
#define WW 128
#define HWSZ (HH*WW)
#define BB 4

typedef __attribute__((ext_vector_type(8))) short short8;
typedef __attribute__((ext_vector_type(16))) float f32x16;

__device__ __forceinline__ ushort bf16_rn(float f) {
    uint u = __builtin_bit_cast(uint, f);
    return (ushort)((u + 0x7fffu + ((u >> 16) & 1u)) >> 16);
}
__device__ __forceinline__ float bf16_f(ushort h) {
    uint u = ((uint)h) << 16;
    return __builtin_bit_cast(float, u);
}
__device__ __forceinline__ uint pack_bf(float v) {
    ushort h = bf16_rn(v);
    ushort l = bf16_rn(v - bf16_f(h));
    return ((uint)h << 16) | (uint)l;
}

// ---------------------------------------------------------------------------
// Weight prep -> FRAGMENT-READY layout:
//   dst = kc*32*OCpad + ks*16*OCpad + oc*16 + lhi*8 + j
// ---------------------------------------------------------------------------
__global__ __launch_bounds__(256) void prep_wf_k(const float* __restrict__ w,
                                                 ushort* __restrict__ whiF,
                                                 ushort* __restrict__ wloF,
                                                 int OC, int K, int OCpad, int KPAD) {
    int idx = blockIdx.x * 256 + threadIdx.x;
    if (idx >= OCpad * KPAD) return;
    int oc = idx / KPAD, k = idx - oc * KPAD;
    float v = (oc < OC && k < K) ? w[(size_t)oc * K + k] : 0.f;
    ushort h = bf16_rn(v);
    ushort l = bf16_rn(v - bf16_f(h));
    const int kc = k >> 5, r = k & 31;
    const int ks = r >> 4, lhi = (r >> 3) & 1, j = r & 7;
    const size_t dst = (size_t)kc * 32 * OCpad + ks * 16 * OCpad + oc * 16 + lhi * 8 + j;
    whiF[dst] = h;
    wloF[dst] = l;
}

// ---------------------------------------------------------------------------
// Deform weight prep -> fragment-ready (k-major kidx = k9*64 + c).
// ---------------------------------------------------------------------------
__global__ __launch_bounds__(256) void prep_wdf_k(const float* __restrict__ w,
                                                  ushort* __restrict__ whiF,
                                                  ushort* __restrict__ wloF) {
    int idx = blockIdx.x * 256 + threadIdx.x;
    if (idx >= 64 * 576) return;
    int oc = idx / 576, rem = idx - oc * 576;
    int k9 = rem / 64, c = rem & 63;
    float v = w[(size_t)oc * 576 + c * 9 + k9];
    ushort h = bf16_rn(v);
    ushort l = bf16_rn(v - bf16_f(h));
    const int half = c >> 5, r = c & 31;
    const int ks = r >> 4, lhi = (r >> 3) & 1, j = r & 7;
    const size_t dst = (size_t)((k9 * 2 + half) * 2 + ks) * 1024 + oc * 16 + lhi * 8 + j;
    whiF[dst] = h;
    wloF[dst] = l;
}

// ---------------------------------------------------------------------------
// Input concat+pack -> packed uint planes [b][132][H][W].
// ---------------------------------------------------------------------------
__global__ __launch_bounds__(256) void cvt_in_k(const float* __restrict__ xfw,
                                                const float* __restrict__ xcur,
                                                const float* __restrict__ flow,
                                                uint* __restrict__ concatP) {
    int idx = blockIdx.x * 256 + threadIdx.x;
    if (idx >= BB * 132 * HWSZ) return;
    int b = idx / (132 * HWSZ);
    int rem = idx - b * 132 * HWSZ;
    int c = rem / HWSZ, pix = rem - c * HWSZ;
    float v = 0.f;
    if (c < 64)       v = xfw [((size_t)b * 64 + c)       * HWSZ + pix];
    else if (c < 128) v = xcur[((size_t)b * 64 + c - 64)  * HWSZ + pix];
    else if (c < 130) v = flow[((size_t)b * 2  + c - 128) * HWSZ + pix];
    concatP[idx] = pack_bf(v);
}

// ---------------------------------------------------------------------------
// Pack x into gather-friendly float4: xP[b][dg][pix]
// ---------------------------------------------------------------------------
__global__ __launch_bounds__(256) void pack_x_k(const float* __restrict__ x,
                                                float4* __restrict__ xP) {
    int idx = blockIdx.x * 256 + threadIdx.x;
    if (idx >= BB * 16 * HWSZ) return;
    int b = idx / (16 * HWSZ);
    int rem = idx - b * 16 * HWSZ;
    int dg = rem / HWSZ, pix = rem - dg * HWSZ;
    const float* src = x + ((size_t)b * 64 + dg * 4) * HWSZ + pix;
    float4 v;
    v.x = src[0];
    v.y = src[HWSZ];
    v.z = src[2 * HWSZ];
    v.w = src[3 * HWSZ];
    xP[idx] = v;
}

// ---------------------------------------------------------------------------
// Implicit-GEMM MFMA conv3x3, split-bf16x2, packed-uint activations.
// 512 threads = 8 waves (2M x 4N). Block tile: NG*64 oc x 128 px (one row).
// 1D grid with XCD-chunked swizzle: orig = row*NGY + gy; each XCD owns a
// contiguous row range x all oc-groups -> weights + halo rows L2-resident.
// A: fragment-ready coalesced global loads, issued BEFORE B-prefetch so the
//    MFMA phase's vmcnt wait does not drain the prefetch.
// B: LDS ping-pong double-buffer, 1 barrier/chunk.
// ---------------------------------------------------------------------------
template<int NG, int NGY, int IC, int KPAD, int OCPAD, int MODE>
__global__ __launch_bounds__(512, 4) void conv_v7(
    const uint* __restrict__ inP,
    const ushort* __restrict__ whiF, const ushort* __restrict__ wloF,
    const float* __restrict__ bias, void* __restrict__ outPtr,
    const float* __restrict__ flow)
{
    constexpr int NCHUNK = KPAD / 32;
    constexpr int LDK = 40;
    constexpr int NBLK = BB * HH * NGY;
    constexpr int PER = NBLK / 8;

    __shared__ ushort iHi[2][128 * LDK], iLo[2][128 * LDK];

    const int tid = threadIdx.x;
    const int id  = blockIdx.x;
    const int orig = (id & 7) * PER + (id >> 3);    // XCD-chunked (bijective)
    const int row  = orig / NGY;
    const int gy   = orig - row * NGY;
    const int b = row >> 7, y = row & 127;
    const int o0 = gy * (NG * 64);

    const int wave = tid >> 6, lane = tid & 63;
    const int wm = wave >> 2, wn = wave & 3;     // 2 x 4 wave grid
    const int l31 = lane & 31, lhi = lane >> 5;
    const int spx = tid & 127;                    // staged px
    const int sko = __builtin_amdgcn_readfirstlane(tid >> 7);  // k-octet 0..3

    f32x16 acc[NG] = {};
    uint pb[8];

    auto FETCH = [&](int kc) {
        #pragma unroll
        for (int j = 0; j < 8; ++j) {
            const int k  = kc * 32 + sko * 8 + j;   // scalar
            const int ic = k / 9;
            const int kk = k - ic * 9;
            const int ky = kk / 3;
            const int kx = kk - ky * 3;
            const int gyy = y + ky - 1;             // scalar
            const uint* prow = inP + ((size_t)b * IC + ic) * HWSZ + gyy * WW;
            const int gx = spx + kx - 1;            // vector
            uint u = 0;
            if ((unsigned)gyy < (unsigned)HH && (unsigned)gx < (unsigned)WW)
                u = prow[gx];
            pb[j] = u;
        }
    };
    auto WRITE = [&](int buf) {
        short8 ph, pl;
        #pragma unroll
        for (int j = 0; j < 8; ++j) {
            ph[j] = (short)(pb[j] >> 16);
            pl[j] = (short)(pb[j] & 0xffffu);
        }
        *(short8*)&iHi[buf][spx * LDK + sko * 8] = ph;
        *(short8*)&iLo[buf][spx * LDK + sko * 8] = pl;
    };

    FETCH(0);
    WRITE(0);

    for (int kc = 0; kc < NCHUNK; ++kc) {
        __syncthreads();                       // buf[kc&1] visible to all
        const int cur = kc & 1;

        // A fragments FIRST (MFMA waits only for these; coalesced 1KB/wave)
        short8 afh[2][NG], afl[2][NG];
        #pragma unroll
        for (int ks = 0; ks < 2; ++ks) {
            #pragma unroll
            for (int mg = 0; mg < NG; ++mg) {
                const size_t ga = (size_t)kc * 32 * OCPAD + (size_t)ks * 16 * OCPAD
                                + (o0 + wm * (NG * 32) + mg * 32 + l31) * 16 + lhi * 8;
                afh[ks][mg] = *(const short8*)&whiF[ga];
                afl[ks][mg] = *(const short8*)&wloF[ga];
            }
        }
        // B prefetch for next chunk (stays in flight through the MFMA phase)
        if (kc + 1 < NCHUNK) FETCH(kc + 1);

        // MFMA phase: B from LDS buf[cur]
        #pragma unroll
        for (int ks = 0; ks < 2; ++ks) {
            const int koff = ks * 16 + lhi * 8;
            const int ib = (wn * 32 + l31) * LDK + koff;
            const short8 bh = *(const short8*)&iHi[cur][ib];
            const short8 bl = *(const short8*)&iLo[cur][ib];
            #pragma unroll
            for (int mg = 0; mg < NG; ++mg) {
                acc[mg] = __builtin_amdgcn_mfma_f32_32x32x16_bf16(afh[ks][mg], bh, acc[mg], 0, 0, 0);
                acc[mg] = __builtin_amdgcn_mfma_f32_32x32x16_bf16(afh[ks][mg], bl, acc[mg], 0, 0, 0);
                acc[mg] = __builtin_amdgcn_mfma_f32_32x32x16_bf16(afl[ks][mg], bh, acc[mg], 0, 0, 0);
            }
        }

        // write prefetched B into the other buffer (after MFMA)
        if (kc + 1 < NCHUNK) WRITE(1 - cur);
    }

    // ---- epilogue ----
    const int px = wn * 32 + l31;
    if (MODE == 1) {
        uint* outP = (uint*)outPtr;
        #pragma unroll
        for (int r = 0; r < 16; ++r) {
            const int oc = wm * 32 + (r & 3) + 8 * (r >> 2) + 4 * lhi;
            float v = acc[0][r] + bias[oc];
            v = v >= 0.f ? v : 0.1f * v;
            outP[((size_t)b * 64 + oc) * HWSZ + y * WW + px] = pack_bf(v);
        }
    } else {
        float* outF = (float*)outPtr;
        #pragma unroll
        for (int mg = 0; mg < NG; ++mg) {
            #pragma unroll
            for (int r = 0; r < 16; ++r) {
                const int oc = o0 + wm * (NG * 32) + mg * 32
                             + (r & 3) + 8 * (r >> 2) + 4 * lhi;
                if (oc < 432) {
                    float v = acc[mg][r] + bias[oc];
                    float res;
                    if (oc < 288) {
                        const float fl = flow[(((size_t)b * 2 + ((oc & 1) ? 0 : 1)) * HH + y) * WW + px];
                        res = 10.f * tanhf(v) + fl;
                    } else {
                        res = 1.f / (1.f + expf(-v));
                    }
                    outF[((size_t)b * 432 + oc) * HWSZ + y * WW + px] = res;
                }
            }
        }
    }
}

// ---------------------------------------------------------------------------
// MFMA deformable conv, zero-LDS / zero-barrier. 256 threads = 4 waves (2x2).
// 1D grid (1024) with XCD-chunked swizzle -> each XCD gathers from ~1/8 of x.
// ---------------------------------------------------------------------------
__global__ __launch_bounds__(256, 4) void deform_v5(
    const float4* __restrict__ xP, const float* __restrict__ offm,
    const ushort* __restrict__ wdfh, const ushort* __restrict__ wdfl,
    const float* __restrict__ bias, float* __restrict__ outp)
{
    const int tid = threadIdx.x;
    const int id  = blockIdx.x;
    const int orig = (id & 7) * 128 + (id >> 3);   // 1024 blocks, bijective
    const int x0 = (orig & 1) * 64;
    const int rl = orig >> 1;
    const int y = rl & 127, b = rl >> 7;

    const int wave = tid >> 6, lane = tid & 63;
    const int wm = wave >> 1, wn = wave & 1;
    const int l31 = lane & 31, lhi = lane >> 5;

    const int xp  = x0 + wn * 32 + l31;      // this lane's pixel (B column)
    const int pix = y * WW + xp;
    const float* offb = offm + (size_t)b * 432 * HWSZ;
    const float fy = (float)y, fx = (float)xp;

    f32x16 acc = {};

    for (int k9 = 0; k9 < 9; ++k9) {
        const float kyf = (float)(k9 / 3 - 1);
        const float kxf = (float)(k9 % 3 - 1);
        #pragma unroll
        for (int half = 0; half < 2; ++half) {
            const size_t abase = (size_t)((k9 * 2 + half) * 2) * 1024
                               + (wm * 32 + l31) * 16 + lhi * 8;
            const short8 ah0 = *(const short8*)&wdfh[abase];
            const short8 al0 = *(const short8*)&wdfl[abase];
            const short8 ah1 = *(const short8*)&wdfh[abase + 1024];
            const short8 al1 = *(const short8*)&wdfl[abase + 1024];
            #pragma unroll
            for (int ks = 0; ks < 2; ++ks) {
                short8 bf;
                #pragma unroll
                for (int d2 = 0; d2 < 2; ++d2) {
                    const int dg = half * 8 + ks * 4 + lhi * 2 + d2;
                    const float dy = offb[(size_t)(dg * 18 + k9 * 2)     * HWSZ + pix];
                    const float dx = offb[(size_t)(dg * 18 + k9 * 2 + 1) * HWSZ + pix];
                    const float mk = offb[(size_t)(288 + dg * 9 + k9)    * HWSZ + pix];
                    const float py = dy + kyf + fy;
                    const float px = dx + kxf + fx;
                    const float y0f = floorf(py), x0f = floorf(px);
                    const float ly = py - y0f, lx = px - x0f;
                    const int yi = (int)y0f, xi = (int)x0f;
                    const float w00 = (1.f - ly) * (1.f - lx), w01 = (1.f - ly) * lx;
                    const float w10 = ly * (1.f - lx),         w11 = ly * lx;
                    const bool vy0 = (unsigned)yi < (unsigned)HH, vy1 = (unsigned)(yi + 1) < (unsigned)HH;
                    const bool vx0 = (unsigned)xi < (unsigned)WW, vx1 = (unsigned)(xi + 1) < (unsigned)WW;
                    const float f00 = (vy0 && vx0) ? w00 * mk : 0.f;
                    const float f01 = (vy0 && vx1) ? w01 * mk : 0.f;
                    const float f10 = (vy1 && vx0) ? w10 * mk : 0.f;
                    const float f11 = (vy1 && vx1) ? w11 * mk : 0.f;
                    const int cy0 = min(max(yi, 0), HH - 1), cy1 = min(max(yi + 1, 0), HH - 1);
                    const int cx0 = min(max(xi, 0), WW - 1), cx1 = min(max(xi + 1, 0), WW - 1);
                    const float4* xg = xP + (size_t)(b * 16 + dg) * HWSZ;
                    const float4 c00 = xg[cy0 * WW + cx0], c01 = xg[cy0 * WW + cx1];
                    const float4 c10 = xg[cy1 * WW + cx0], c11 = xg[cy1 * WW + cx1];
                    bf[d2 * 4 + 0] = (short)bf16_rn(f00 * c00.x + f01 * c01.x + f10 * c10.x + f11 * c11.x);
                    bf[d2 * 4 + 1] = (short)bf16_rn(f00 * c00.y + f01 * c01.y + f10 * c10.y + f11 * c11.y);
                    bf[d2 * 4 + 2] = (short)bf16_rn(f00 * c00.z + f01 * c01.z + f10 * c10.z + f11 * c11.z);
                    bf[d2 * 4 + 3] = (short)bf16_rn(f00 * c00.w + f01 * c01.w + f10 * c10.w + f11 * c11.w);
                }
                if (ks == 0) {
                    acc = __builtin_amdgcn_mfma_f32_32x32x16_bf16(ah0, bf, acc, 0, 0, 0);
                    acc = __builtin_amdgcn_mfma_f32_32x32x16_bf16(al0, bf, acc, 0, 0, 0);
                } else {
                    acc = __builtin_amdgcn_mfma_f32_32x32x16_bf16(ah1, bf, acc, 0, 0, 0);
                    acc = __builtin_amdgcn_mfma_f32_32x32x16_bf16(al1, bf, acc, 0, 0, 0);
                }
            }
        }
    }

    // ---- epilogue ----
    #pragma unroll
    for (int r = 0; r < 16; ++r) {
        const int oc = wm * 32 + (r & 3) + 8 * (r >> 2) + 4 * lhi;
        outp[(((size_t)b * 64 + oc) * HH + y) * WW + xp] = acc[r] + bias[oc];
    }
}

// ---------------------------------------------------------------------------
extern "C" void kernel_launch(void* const* d_in, const int* in_sizes, int n_in,
                              void* d_out, int out_size, void* d_ws, size_t ws_size,
                              hipStream_t stream) {
    const float* x    = (const float*)d_in[0];
    const float* xfw  = (const float*)d_in[1];
    const float* xcur = (const float*)d_in[2];
    const float* flow = (const float*)d_in[3];
    const float* w0   = (const float*)d_in[4];
    const float* b0   = (const float*)d_in[5];
    const float* w1   = (const float*)d_in[6];
    const float* b1   = (const float*)d_in[7];
    const float* w2   = (const float*)d_in[8];
    const float* b2   = (const float*)d_in[9];
    const float* w3   = (const float*)d_in[10];
    const float* b3   = (const float*)d_in[11];
    const float* wdcn = (const float*)d_in[12];
    const float* bdcn = (const float*)d_in[13];
    float* out = (float*)d_out;

    // workspace layout (aliased; stream order makes it safe)
    float* offm   = (float*)d_ws;
    uint* concatP = (uint*)d_ws;
    uint* h0P     = (uint*)((char*)d_ws + (size_t)BB * 432 * HWSZ * 4);
    uint* h1P     = h0P + (size_t)BB * 64 * HWSZ;
    float4* xP    = (float4*)h1P;
    ushort* wp    = (ushort*)(h1P + (size_t)BB * 64 * HWSZ);
    ushort* wdh  = wp;                 ushort* wdl  = wdh + 64 * 576;
    ushort* w0hi = wdl + 64 * 576;     ushort* w0lo = w0hi + 64 * 1184;
    ushort* w1hi = w0lo + 64 * 1184;   ushort* w1lo = w1hi + 64 * 576;
    ushort* w2hi = w1lo + 64 * 576;    ushort* w2lo = w2hi + 64 * 576;
    ushort* w3hi = w2lo + 64 * 576;    ushort* w3lo = w3hi + (size_t)512 * 576;
    uint* h2P = h0P;   // conv2 output reuses h0P

    prep_wf_k<<<dim3((64 * 1184 + 255) / 256), dim3(256), 0, stream>>>(w0, w0hi, w0lo, 64, 1170, 64, 1184);
    prep_wf_k<<<dim3((64 * 576 + 255) / 256),  dim3(256), 0, stream>>>(w1, w1hi, w1lo, 64, 576, 64, 576);
    prep_wf_k<<<dim3((64 * 576 + 255) / 256),  dim3(256), 0, stream>>>(w2, w2hi, w2lo, 64, 576, 64, 576);
    prep_wf_k<<<dim3((512 * 576 + 255) / 256), dim3(256), 0, stream>>>(w3, w3hi, w3lo, 432, 576, 512, 576);
    prep_wdf_k<<<dim3((64 * 576 + 255) / 256), dim3(256), 0, stream>>>(wdcn, wdh, wdl);
    cvt_in_k<<<dim3((BB * 132 * HWSZ + 255) / 256), dim3(256), 0, stream>>>(xfw, xcur, flow, concatP);

    conv_v7<1, 1, 132, 1184, 64, 1><<<dim3(BB * HH), dim3(512), 0, stream>>>(concatP, w0hi, w0lo, b0, h0P, nullptr);
    conv_v7<1, 1, 64, 576, 64, 1><<<dim3(BB * HH), dim3(512), 0, stream>>>(h0P, w1hi, w1lo, b1, h1P, nullptr);
    conv_v7<1, 1, 64, 576, 64, 1><<<dim3(BB * HH), dim3(512), 0, stream>>>(h1P, w2hi, w2lo, b2, h2P, nullptr);
    pack_x_k<<<dim3((BB * 16 * HWSZ + 255) / 256), dim3(256), 0, stream>>>(x, xP);
    conv_v7<2, 4, 64, 576, 512, 2><<<dim3(BB * HH * 4), dim3(512), 0, stream>>>(h2P, w3hi, w3lo, b3, offm, flow);

    deform_v5<<<dim3(1024), dim3(256), 0, stream>>>(xP, offm, wdh, wdl, bdcn, out);
}

// Round 8
// 491.765 us; speedup vs baseline: 1.6166x; 1.2069x over previous
//
#include <hip/hip_runtime.h>
#include <hip/hip_bf16.h>
#include <cmath>

#define HH 128
#define WW 128
#define HWSZ (HH*WW)
#define BB 4

typedef __attribute__((ext_vector_type(8))) short short8;
typedef _Float16 half8 __attribute__((ext_vector_type(8)));
typedef __attribute__((ext_vector_type(16))) float f32x16;

__device__ __forceinline__ ushort f16_rn(float f) {
    _Float16 h = (_Float16)f;
    return __builtin_bit_cast(ushort, h);
}
__device__ __forceinline__ float f16_f(ushort u) {
    return (float)__builtin_bit_cast(_Float16, u);
}

// ---------------------------------------------------------------------------
// Weight prep -> FRAGMENT-READY fp16 hi/lo:
//   dst = kc*32*OCpad + ks*16*OCpad + oc*16 + lhi*8 + j
// ---------------------------------------------------------------------------
__global__ __launch_bounds__(256) void prep_wf_k(const float* __restrict__ w,
                                                 ushort* __restrict__ whiF,
                                                 ushort* __restrict__ wloF,
                                                 int OC, int K, int OCpad, int KPAD) {
    int idx = blockIdx.x * 256 + threadIdx.x;
    if (idx >= OCpad * KPAD) return;
    int oc = idx / KPAD, k = idx - oc * KPAD;
    float v = (oc < OC && k < K) ? w[(size_t)oc * K + k] : 0.f;
    ushort h = f16_rn(v);
    ushort l = f16_rn(v - f16_f(h));
    const int kc = k >> 5, r = k & 31;
    const int ks = r >> 4, lhi = (r >> 3) & 1, j = r & 7;
    const size_t dst = (size_t)kc * 32 * OCpad + ks * 16 * OCpad + oc * 16 + lhi * 8 + j;
    whiF[dst] = h;
    wloF[dst] = l;
}

// ---------------------------------------------------------------------------
// Deform weight prep -> fragment-ready fp16 (k-major kidx = k9*64 + c).
// ---------------------------------------------------------------------------
__global__ __launch_bounds__(256) void prep_wdf_k(const float* __restrict__ w,
                                                  ushort* __restrict__ whiF,
                                                  ushort* __restrict__ wloF) {
    int idx = blockIdx.x * 256 + threadIdx.x;
    if (idx >= 64 * 576) return;
    int oc = idx / 576, rem = idx - oc * 576;
    int k9 = rem / 64, c = rem & 63;
    float v = w[(size_t)oc * 576 + c * 9 + k9];
    ushort h = f16_rn(v);
    ushort l = f16_rn(v - f16_f(h));
    const int hv = c >> 5, r = c & 31;
    const int ks = r >> 4, lhi = (r >> 3) & 1, j = r & 7;
    const size_t dst = (size_t)((k9 * 2 + hv) * 2 + ks) * 1024 + oc * 16 + lhi * 8 + j;
    whiF[dst] = h;
    wloF[dst] = l;
}

// ---------------------------------------------------------------------------
// Input concat -> single fp16 planes [b][132][H][W].
// ---------------------------------------------------------------------------
__global__ __launch_bounds__(256) void cvt_in_k(const float* __restrict__ xfw,
                                                const float* __restrict__ xcur,
                                                const float* __restrict__ flow,
                                                ushort* __restrict__ concatP) {
    int idx = blockIdx.x * 256 + threadIdx.x;
    if (idx >= BB * 132 * HWSZ) return;
    int b = idx / (132 * HWSZ);
    int rem = idx - b * 132 * HWSZ;
    int c = rem / HWSZ, pix = rem - c * HWSZ;
    float v = 0.f;
    if (c < 64)       v = xfw [((size_t)b * 64 + c)       * HWSZ + pix];
    else if (c < 128) v = xcur[((size_t)b * 64 + c - 64)  * HWSZ + pix];
    else if (c < 130) v = flow[((size_t)b * 2  + c - 128) * HWSZ + pix];
    concatP[idx] = f16_rn(v);
}

// ---------------------------------------------------------------------------
// Pack x into gather-friendly float4: xP[b][dg][pix]
// ---------------------------------------------------------------------------
__global__ __launch_bounds__(256) void pack_x_k(const float* __restrict__ x,
                                                float4* __restrict__ xP) {
    int idx = blockIdx.x * 256 + threadIdx.x;
    if (idx >= BB * 16 * HWSZ) return;
    int b = idx / (16 * HWSZ);
    int rem = idx - b * 16 * HWSZ;
    int dg = rem / HWSZ, pix = rem - dg * HWSZ;
    const float* src = x + ((size_t)b * 64 + dg * 4) * HWSZ + pix;
    float4 v;
    v.x = src[0];
    v.y = src[HWSZ];
    v.z = src[2 * HWSZ];
    v.w = src[3 * HWSZ];
    xP[idx] = v;
}

// ---------------------------------------------------------------------------
// Implicit-GEMM MFMA conv3x3, fp16 2-term split (A hi/lo x B single).
// 512 threads = 8 waves (2M x 4N); tile NG*64 oc x 128 px (one image row).
// XCD-chunked 1D grid; A fragment-ready coalesced global (issued first);
// B single-fp16 LDS ping-pong, 1 barrier/chunk.
// MODE 1: lrelu, fp16-plane output.  MODE 2: conv3 epilogue, fp32 output.
// ---------------------------------------------------------------------------
template<int NG, int NGY, int IC, int KPAD, int OCPAD, int MODE>
__global__ __launch_bounds__(512, 4) void conv_v8(
    const ushort* __restrict__ inP,
    const ushort* __restrict__ whiF, const ushort* __restrict__ wloF,
    const float* __restrict__ bias, void* __restrict__ outPtr,
    const float* __restrict__ flow)
{
    constexpr int NCHUNK = KPAD / 32;
    constexpr int LDK = 40;
    constexpr int NBLK = BB * HH * NGY;
    constexpr int PER = NBLK / 8;

    __shared__ ushort iB[2][128 * LDK];

    const int tid = threadIdx.x;
    const int id  = blockIdx.x;
    const int orig = (id & 7) * PER + (id >> 3);    // XCD-chunked (bijective)
    const int row  = orig / NGY;
    const int gy   = orig - row * NGY;
    const int b = row >> 7, y = row & 127;
    const int o0 = gy * (NG * 64);

    const int wave = tid >> 6, lane = tid & 63;
    const int wm = wave >> 2, wn = wave & 3;     // 2 x 4 wave grid
    const int l31 = lane & 31, lhi = lane >> 5;
    const int spx = tid & 127;                    // staged px
    const int sko = __builtin_amdgcn_readfirstlane(tid >> 7);  // k-octet 0..3

    f32x16 acc[NG] = {};
    ushort pb[8];

    auto FETCH = [&](int kc) {
        #pragma unroll
        for (int j = 0; j < 8; ++j) {
            const int k  = kc * 32 + sko * 8 + j;   // scalar
            const int ic = k / 9;
            const int kk = k - ic * 9;
            const int ky = kk / 3;
            const int kx = kk - ky * 3;
            const int gyy = y + ky - 1;             // scalar
            const ushort* prow = inP + ((size_t)b * IC + ic) * HWSZ + gyy * WW;
            const int gx = spx + kx - 1;            // vector
            ushort u = 0;
            if ((unsigned)gyy < (unsigned)HH && (unsigned)gx < (unsigned)WW)
                u = prow[gx];
            pb[j] = u;
        }
    };
    auto WRITE = [&](int buf) {
        short8 pw;
        #pragma unroll
        for (int j = 0; j < 8; ++j) pw[j] = (short)pb[j];
        *(short8*)&iB[buf][spx * LDK + sko * 8] = pw;
    };

    FETCH(0);
    WRITE(0);

    for (int kc = 0; kc < NCHUNK; ++kc) {
        __syncthreads();                       // buf[kc&1] visible to all
        const int cur = kc & 1;

        // A fragments FIRST (contiguous 1KB/wave, L2-hot)
        half8 afh[2][NG], afl[2][NG];
        #pragma unroll
        for (int ks = 0; ks < 2; ++ks) {
            #pragma unroll
            for (int mg = 0; mg < NG; ++mg) {
                const size_t ga = (size_t)kc * 32 * OCPAD + (size_t)ks * 16 * OCPAD
                                + (o0 + wm * (NG * 32) + mg * 32 + l31) * 16 + lhi * 8;
                afh[ks][mg] = __builtin_bit_cast(half8, *(const short8*)&whiF[ga]);
                afl[ks][mg] = __builtin_bit_cast(half8, *(const short8*)&wloF[ga]);
            }
        }
        // B prefetch for next chunk (stays in flight through MFMA phase)
        if (kc + 1 < NCHUNK) FETCH(kc + 1);

        // MFMA phase: B single fp16 from LDS buf[cur]
        #pragma unroll
        for (int ks = 0; ks < 2; ++ks) {
            const int koff = ks * 16 + lhi * 8;
            const int ib = (wn * 32 + l31) * LDK + koff;
            const half8 bh = __builtin_bit_cast(half8, *(const short8*)&iB[cur][ib]);
            #pragma unroll
            for (int mg = 0; mg < NG; ++mg) {
                acc[mg] = __builtin_amdgcn_mfma_f32_32x32x16_f16(afh[ks][mg], bh, acc[mg], 0, 0, 0);
                acc[mg] = __builtin_amdgcn_mfma_f32_32x32x16_f16(afl[ks][mg], bh, acc[mg], 0, 0, 0);
            }
        }

        // write prefetched B into the other buffer (after MFMA)
        if (kc + 1 < NCHUNK) WRITE(1 - cur);
    }

    // ---- epilogue ----
    const int px = wn * 32 + l31;
    if (MODE == 1) {
        ushort* outP = (ushort*)outPtr;
        #pragma unroll
        for (int r = 0; r < 16; ++r) {
            const int oc = wm * 32 + (r & 3) + 8 * (r >> 2) + 4 * lhi;
            float v = acc[0][r] + bias[oc];
            v = v >= 0.f ? v : 0.1f * v;
            outP[((size_t)b * 64 + oc) * HWSZ + y * WW + px] = f16_rn(v);
        }
    } else {
        float* outF = (float*)outPtr;
        #pragma unroll
        for (int mg = 0; mg < NG; ++mg) {
            #pragma unroll
            for (int r = 0; r < 16; ++r) {
                const int oc = o0 + wm * (NG * 32) + mg * 32
                             + (r & 3) + 8 * (r >> 2) + 4 * lhi;
                if (oc < 432) {
                    float v = acc[mg][r] + bias[oc];
                    float res;
                    if (oc < 288) {
                        const float fl = flow[(((size_t)b * 2 + ((oc & 1) ? 0 : 1)) * HH + y) * WW + px];
                        res = 10.f * tanhf(v) + fl;
                    } else {
                        res = 1.f / (1.f + expf(-v));
                    }
                    outF[((size_t)b * 432 + oc) * HWSZ + y * WW + px] = res;
                }
            }
        }
    }
}

// ---------------------------------------------------------------------------
// MFMA deformable conv v6: no duplicated sampling. 256 threads = 4 waves.
// wm splits the k9 range (0-4 / 5-8); each wave computes the full M=64 via
// two 32-row accumulators; one LDS reduction + single barrier at the end.
// Each lane samples ITS OWN B-fragment (2 dgs x 4 ch at its pixel, fp16).
// ---------------------------------------------------------------------------
__global__ __launch_bounds__(256, 4) void deform_v6(
    const float4* __restrict__ xP, const float* __restrict__ offm,
    const ushort* __restrict__ wdfh, const ushort* __restrict__ wdfl,
    const float* __restrict__ bias, float* __restrict__ outp)
{
    __shared__ float red[2][64][34];   // [wn][lane][mg*16+r], padded

    const int tid = threadIdx.x;
    const int id  = blockIdx.x;
    const int orig = (id & 7) * 128 + (id >> 3);   // 1024 blocks, bijective
    const int x0 = (orig & 1) * 64;
    const int rl = orig >> 1;
    const int y = rl & 127, b = rl >> 7;

    const int wave = tid >> 6, lane = tid & 63;
    const int wm = wave >> 1, wn = wave & 1;
    const int l31 = lane & 31, lhi = lane >> 5;

    const int xp  = x0 + wn * 32 + l31;      // this lane's pixel (B column)
    const int pix = y * WW + xp;
    const float* offb = offm + (size_t)b * 432 * HWSZ;
    const float fy = (float)y, fx = (float)xp;

    f32x16 acc[2] = {};

    const int k9lo = wm ? 5 : 0;
    const int k9hi = wm ? 9 : 5;
    for (int k9 = k9lo; k9 < k9hi; ++k9) {
        const float kyf = (float)(k9 / 3 - 1);
        const float kxf = (float)(k9 % 3 - 1);
        #pragma unroll
        for (int hv = 0; hv < 2; ++hv) {
            #pragma unroll
            for (int ks = 0; ks < 2; ++ks) {
                // sample this lane's B-fragment: dgs {hv*8+ks*4+lhi*2, +1}
                short8 bfs;
                #pragma unroll
                for (int d2 = 0; d2 < 2; ++d2) {
                    const int dg = hv * 8 + ks * 4 + lhi * 2 + d2;
                    const float dy = offb[(size_t)(dg * 18 + k9 * 2)     * HWSZ + pix];
                    const float dx = offb[(size_t)(dg * 18 + k9 * 2 + 1) * HWSZ + pix];
                    const float mk = offb[(size_t)(288 + dg * 9 + k9)    * HWSZ + pix];
                    const float py = dy + kyf + fy;
                    const float px = dx + kxf + fx;
                    const float y0f = floorf(py), x0f = floorf(px);
                    const float ly = py - y0f, lx = px - x0f;
                    const int yi = (int)y0f, xi = (int)x0f;
                    const float w00 = (1.f - ly) * (1.f - lx), w01 = (1.f - ly) * lx;
                    const float w10 = ly * (1.f - lx),         w11 = ly * lx;
                    const bool vy0 = (unsigned)yi < (unsigned)HH, vy1 = (unsigned)(yi + 1) < (unsigned)HH;
                    const bool vx0 = (unsigned)xi < (unsigned)WW, vx1 = (unsigned)(xi + 1) < (unsigned)WW;
                    const float f00 = (vy0 && vx0) ? w00 * mk : 0.f;
                    const float f01 = (vy0 && vx1) ? w01 * mk : 0.f;
                    const float f10 = (vy1 && vx0) ? w10 * mk : 0.f;
                    const float f11 = (vy1 && vx1) ? w11 * mk : 0.f;
                    const int cy0 = min(max(yi, 0), HH - 1), cy1 = min(max(yi + 1, 0), HH - 1);
                    const int cx0 = min(max(xi, 0), WW - 1), cx1 = min(max(xi + 1, 0), WW - 1);
                    const float4* xg = xP + (size_t)(b * 16 + dg) * HWSZ;
                    const float4 c00 = xg[cy0 * WW + cx0], c01 = xg[cy0 * WW + cx1];
                    const float4 c10 = xg[cy1 * WW + cx0], c11 = xg[cy1 * WW + cx1];
                    bfs[d2 * 4 + 0] = (short)f16_rn(f00 * c00.x + f01 * c01.x + f10 * c10.x + f11 * c11.x);
                    bfs[d2 * 4 + 1] = (short)f16_rn(f00 * c00.y + f01 * c01.y + f10 * c10.y + f11 * c11.y);
                    bfs[d2 * 4 + 2] = (short)f16_rn(f00 * c00.z + f01 * c01.z + f10 * c10.z + f11 * c11.z);
                    bfs[d2 * 4 + 3] = (short)f16_rn(f00 * c00.w + f01 * c01.w + f10 * c10.w + f11 * c11.w);
                }
                const half8 bf = __builtin_bit_cast(half8, bfs);
                const size_t abase = (size_t)((k9 * 2 + hv) * 2 + ks) * 1024 + l31 * 16 + lhi * 8;
                #pragma unroll
                for (int mg = 0; mg < 2; ++mg) {
                    const half8 ah = __builtin_bit_cast(half8, *(const short8*)&wdfh[abase + mg * 512]);
                    const half8 al = __builtin_bit_cast(half8, *(const short8*)&wdfl[abase + mg * 512]);
                    acc[mg] = __builtin_amdgcn_mfma_f32_32x32x16_f16(ah, bf, acc[mg], 0, 0, 0);
                    acc[mg] = __builtin_amdgcn_mfma_f32_32x32x16_f16(al, bf, acc[mg], 0, 0, 0);
                }
            }
        }
    }

    // ---- cross-wm reduction + write ----
    if (wm == 1) {
        #pragma unroll
        for (int mg = 0; mg < 2; ++mg)
            #pragma unroll
            for (int r = 0; r < 16; ++r)
                red[wn][lane][mg * 16 + r] = acc[mg][r];
    }
    __syncthreads();
    if (wm == 0) {
        #pragma unroll
        for (int mg = 0; mg < 2; ++mg)
            #pragma unroll
            for (int r = 0; r < 16; ++r) {
                const int oc = mg * 32 + (r & 3) + 8 * (r >> 2) + 4 * lhi;
                const float v = acc[mg][r] + red[wn][lane][mg * 16 + r] + bias[oc];
                outp[(((size_t)b * 64 + oc) * HH + y) * WW + xp] = v;
            }
    }
}

// ---------------------------------------------------------------------------
extern "C" void kernel_launch(void* const* d_in, const int* in_sizes, int n_in,
                              void* d_out, int out_size, void* d_ws, size_t ws_size,
                              hipStream_t stream) {
    const float* x    = (const float*)d_in[0];
    const float* xfw  = (const float*)d_in[1];
    const float* xcur = (const float*)d_in[2];
    const float* flow = (const float*)d_in[3];
    const float* w0   = (const float*)d_in[4];
    const float* b0   = (const float*)d_in[5];
    const float* w1   = (const float*)d_in[6];
    const float* b1   = (const float*)d_in[7];
    const float* w2   = (const float*)d_in[8];
    const float* b2   = (const float*)d_in[9];
    const float* w3   = (const float*)d_in[10];
    const float* b3   = (const float*)d_in[11];
    const float* wdcn = (const float*)d_in[12];
    const float* bdcn = (const float*)d_in[13];
    float* out = (float*)d_out;

    // workspace layout (aliased; stream order makes it safe):
    //   [0, 113.2MB)  offm fp32 (concatP fp16 17.3MB aliases head; dead
    //                 before conv3 writes offm)
    //   then h0P fp16 8.4MB (conv2 reuses = h2P) | h1P fp16 8.4MB |
    //   xP float4 16.8MB | fragment-ready fp16 weights ~1.9MB
    float* offm    = (float*)d_ws;
    ushort* concatP = (ushort*)d_ws;
    ushort* h0P    = (ushort*)((char*)d_ws + (size_t)BB * 432 * HWSZ * 4);
    ushort* h1P    = h0P + (size_t)BB * 64 * HWSZ;
    float4* xP     = (float4*)(h1P + (size_t)BB * 64 * HWSZ);
    ushort* wp     = (ushort*)(xP + (size_t)BB * 16 * HWSZ);
    ushort* wdh  = wp;                 ushort* wdl  = wdh + 64 * 576;
    ushort* w0hi = wdl + 64 * 576;     ushort* w0lo = w0hi + 64 * 1184;
    ushort* w1hi = w0lo + 64 * 1184;   ushort* w1lo = w1hi + 64 * 576;
    ushort* w2hi = w1lo + 64 * 576;    ushort* w2lo = w2hi + 64 * 576;
    ushort* w3hi = w2lo + 64 * 576;    ushort* w3lo = w3hi + (size_t)512 * 576;
    ushort* h2P = h0P;   // conv2 output reuses h0P

    prep_wf_k<<<dim3((64 * 1184 + 255) / 256), dim3(256), 0, stream>>>(w0, w0hi, w0lo, 64, 1170, 64, 1184);
    prep_wf_k<<<dim3((64 * 576 + 255) / 256),  dim3(256), 0, stream>>>(w1, w1hi, w1lo, 64, 576, 64, 576);
    prep_wf_k<<<dim3((64 * 576 + 255) / 256),  dim3(256), 0, stream>>>(w2, w2hi, w2lo, 64, 576, 64, 576);
    prep_wf_k<<<dim3((512 * 576 + 255) / 256), dim3(256), 0, stream>>>(w3, w3hi, w3lo, 432, 576, 512, 576);
    prep_wdf_k<<<dim3((64 * 576 + 255) / 256), dim3(256), 0, stream>>>(wdcn, wdh, wdl);
    cvt_in_k<<<dim3((BB * 132 * HWSZ + 255) / 256), dim3(256), 0, stream>>>(xfw, xcur, flow, concatP);

    conv_v8<1, 1, 132, 1184, 64, 1><<<dim3(BB * HH), dim3(512), 0, stream>>>(concatP, w0hi, w0lo, b0, h0P, nullptr);
    conv_v8<1, 1, 64, 576, 64, 1><<<dim3(BB * HH), dim3(512), 0, stream>>>(h0P, w1hi, w1lo, b1, h1P, nullptr);
    conv_v8<1, 1, 64, 576, 64, 1><<<dim3(BB * HH), dim3(512), 0, stream>>>(h1P, w2hi, w2lo, b2, h2P, nullptr);
    pack_x_k<<<dim3((BB * 16 * HWSZ + 255) / 256), dim3(256), 0, stream>>>(x, xP);
    conv_v8<2, 4, 64, 576, 512, 2><<<dim3(BB * HH * 4), dim3(512), 0, stream>>>(h2P, w3hi, w3lo, b3, offm, flow);

    deform_v6<<<dim3(1024), dim3(256), 0, stream>>>(xP, offm, wdh, wdl, bdcn, out);
}

// Round 9
// 417.957 us; speedup vs baseline: 1.9021x; 1.1766x over previous
//
#include <hip/hip_runtime.h>
#include <hip/hip_bf16.h>
#include <cmath>

#define HH 128
#define WW 128
#define HWSZ (HH*WW)
#define BB 4

typedef __attribute__((ext_vector_type(8))) short short8;
typedef _Float16 half8 __attribute__((ext_vector_type(8)));
typedef __attribute__((ext_vector_type(16))) float f32x16;

__device__ __forceinline__ ushort f16_rn(float f) {
    _Float16 h = (_Float16)f;
    return __builtin_bit_cast(ushort, h);
}

// ---------------------------------------------------------------------------
// Weight prep -> FRAGMENT-READY fp16 (single plane):
//   dst = kc*32*OCpad + ks*16*OCpad + oc*16 + lhi*8 + j
// ---------------------------------------------------------------------------
__global__ __launch_bounds__(256) void prep_wf_k(const float* __restrict__ w,
                                                 ushort* __restrict__ whiF,
                                                 int OC, int K, int OCpad, int KPAD) {
    int idx = blockIdx.x * 256 + threadIdx.x;
    if (idx >= OCpad * KPAD) return;
    int oc = idx / KPAD, k = idx - oc * KPAD;
    float v = (oc < OC && k < K) ? w[(size_t)oc * K + k] : 0.f;
    const int kc = k >> 5, r = k & 31;
    const int ks = r >> 4, lhi = (r >> 3) & 1, j = r & 7;
    const size_t dst = (size_t)kc * 32 * OCpad + ks * 16 * OCpad + oc * 16 + lhi * 8 + j;
    whiF[dst] = f16_rn(v);
}

// ---------------------------------------------------------------------------
// Deform weight prep -> fragment-ready fp16 (k-major kidx = k9*64 + c).
// ---------------------------------------------------------------------------
__global__ __launch_bounds__(256) void prep_wdf_k(const float* __restrict__ w,
                                                  ushort* __restrict__ whiF) {
    int idx = blockIdx.x * 256 + threadIdx.x;
    if (idx >= 64 * 576) return;
    int oc = idx / 576, rem = idx - oc * 576;
    int k9 = rem / 64, c = rem & 63;
    float v = w[(size_t)oc * 576 + c * 9 + k9];
    const int hv = c >> 5, r = c & 31;
    const int ks = r >> 4, lhi = (r >> 3) & 1, j = r & 7;
    const size_t dst = (size_t)((k9 * 2 + hv) * 2 + ks) * 1024 + oc * 16 + lhi * 8 + j;
    whiF[dst] = f16_rn(v);
}

// ---------------------------------------------------------------------------
// Input concat -> fp16 planes [b][132][H][W] (ch 130,131 zero).
// ---------------------------------------------------------------------------
__global__ __launch_bounds__(256) void cvt_in_k(const float* __restrict__ xfw,
                                                const float* __restrict__ xcur,
                                                const float* __restrict__ flow,
                                                ushort* __restrict__ concatP) {
    int idx = blockIdx.x * 256 + threadIdx.x;
    if (idx >= BB * 132 * HWSZ) return;
    int b = idx / (132 * HWSZ);
    int rem = idx - b * 132 * HWSZ;
    int c = rem / HWSZ, pix = rem - c * HWSZ;
    float v = 0.f;
    if (c < 64)       v = xfw [((size_t)b * 64 + c)       * HWSZ + pix];
    else if (c < 128) v = xcur[((size_t)b * 64 + c - 64)  * HWSZ + pix];
    else if (c < 130) v = flow[((size_t)b * 2  + c - 128) * HWSZ + pix];
    concatP[idx] = f16_rn(v);
}

// ---------------------------------------------------------------------------
// Pack x into gather-friendly float4: xP[b][dg][pix]
// ---------------------------------------------------------------------------
__global__ __launch_bounds__(256) void pack_x_k(const float* __restrict__ x,
                                                float4* __restrict__ xP) {
    int idx = blockIdx.x * 256 + threadIdx.x;
    if (idx >= BB * 16 * HWSZ) return;
    int b = idx / (16 * HWSZ);
    int rem = idx - b * 16 * HWSZ;
    int dg = rem / HWSZ, pix = rem - dg * HWSZ;
    const float* src = x + ((size_t)b * 64 + dg * 4) * HWSZ + pix;
    float4 v;
    v.x = src[0];
    v.y = src[HWSZ];
    v.z = src[2 * HWSZ];
    v.w = src[3 * HWSZ];
    xP[idx] = v;
}

// ---------------------------------------------------------------------------
// conv0/1/2: single-fp16 implicit-GEMM, 2-ROW tile (64 oc x 256 px).
// 512 threads = 8 waves (2M x 4N); each wave 32oc x 64px (2 pg).
// A fragment-ready global (single plane); B fp16 LDS ping-pong, 1 barrier.
// lrelu epilogue, fp16-plane output.
// ---------------------------------------------------------------------------
template<int IC, int KPAD>
__global__ __launch_bounds__(512, 4) void conv_n256(
    const ushort* __restrict__ inP, const ushort* __restrict__ whiF,
    const float* __restrict__ bias, ushort* __restrict__ outP)
{
    constexpr int NCHUNK = KPAD / 32;
    constexpr int LDK = 40;
    constexpr int NBLK = BB * 64;      // 256 blocks (2 rows each)
    constexpr int PER = NBLK / 8;

    __shared__ ushort iB[2][256 * LDK];   // 40 KB

    const int tid = threadIdx.x;
    const int id  = blockIdx.x;
    const int orig = (id & 7) * PER + (id >> 3);   // XCD-chunked bijective
    const int b   = orig >> 6;
    const int y0r = (orig & 63) * 2;

    const int wave = tid >> 6, lane = tid & 63;
    const int wm = wave >> 2, wn = wave & 3;
    const int l31 = lane & 31, lhi = lane >> 5;

    const int px2 = tid & 255;                     // staging slot (row*128+px)
    const int spx = px2 & 127;
    const int srow = __builtin_amdgcn_readfirstlane((tid >> 7) & 1);
    const int skh  = __builtin_amdgcn_readfirstlane(tid >> 8);   // 16-k half

    f32x16 acc[2] = {};
    ushort pb[16];

    auto FETCH = [&](int kc) {
        #pragma unroll
        for (int j = 0; j < 16; ++j) {
            const int k  = kc * 32 + skh * 16 + j;   // wave-uniform
            const int ic = k / 9;
            const int kk = k - ic * 9;
            const int ky = kk / 3;
            const int kx = kk - ky * 3;
            const int gyy = y0r + srow + ky - 1;     // wave-uniform
            const int gx = spx + kx - 1;             // per-lane
            ushort u = 0;
            if ((unsigned)gyy < (unsigned)HH && (unsigned)gx < (unsigned)WW)
                u = inP[((size_t)b * IC + ic) * HWSZ + gyy * WW + gx];
            pb[j] = u;
        }
    };
    auto WRITE = [&](int buf) {
        short8 w0v, w1v;
        #pragma unroll
        for (int j = 0; j < 8; ++j) { w0v[j] = (short)pb[j]; w1v[j] = (short)pb[8 + j]; }
        *(short8*)&iB[buf][px2 * LDK + skh * 16]     = w0v;
        *(short8*)&iB[buf][px2 * LDK + skh * 16 + 8] = w1v;
    };

    FETCH(0);
    WRITE(0);

    for (int kc = 0; kc < NCHUNK; ++kc) {
        __syncthreads();
        const int cur = kc & 1;

        // A fragments first (single plane, both ks), then B prefetch
        half8 af[2];
        #pragma unroll
        for (int ks = 0; ks < 2; ++ks) {
            const size_t ga = (size_t)kc * 32 * 64 + (size_t)ks * 16 * 64
                            + (wm * 32 + l31) * 16 + lhi * 8;
            af[ks] = __builtin_bit_cast(half8, *(const short8*)&whiF[ga]);
        }
        if (kc + 1 < NCHUNK) FETCH(kc + 1);

        #pragma unroll
        for (int ks = 0; ks < 2; ++ks) {
            const int koff = ks * 16 + lhi * 8;
            #pragma unroll
            for (int pg = 0; pg < 2; ++pg) {
                const int ib = (pg * 128 + wn * 32 + l31) * LDK + koff;
                const half8 bh = __builtin_bit_cast(half8, *(const short8*)&iB[cur][ib]);
                acc[pg] = __builtin_amdgcn_mfma_f32_32x32x16_f16(af[ks], bh, acc[pg], 0, 0, 0);
            }
        }

        if (kc + 1 < NCHUNK) WRITE(1 - cur);
    }

    // ---- epilogue: 2 rows ----
    const int px = wn * 32 + l31;
    #pragma unroll
    for (int pg = 0; pg < 2; ++pg) {
        const int y = y0r + pg;
        #pragma unroll
        for (int r = 0; r < 16; ++r) {
            const int oc = wm * 32 + (r & 3) + 8 * (r >> 2) + 4 * lhi;
            float v = acc[pg][r] + bias[oc];
            v = v >= 0.f ? v : 0.1f * v;
            outP[((size_t)b * 64 + oc) * HWSZ + y * WW + px] = f16_rn(v);
        }
    }
}

// ---------------------------------------------------------------------------
// conv3: single-fp16, M-tile 256 (NG=4) x 128 px, NGY=2, 512 threads.
// Per ks: A loads (4 x dwordx4) -> half B-prefetch -> 4 MFMA.
// Epilogue: 10*tanh + reversed flow | sigmoid, fp32 output.
// ---------------------------------------------------------------------------
template<int KPAD>
__global__ __launch_bounds__(512, 4) void conv_m512(
    const ushort* __restrict__ inP, const ushort* __restrict__ whiF,
    const float* __restrict__ bias, float* __restrict__ outF,
    const float* __restrict__ flow)
{
    constexpr int NCHUNK = KPAD / 32;
    constexpr int LDK = 40;
    constexpr int OCPAD = 512;
    constexpr int NBLK = BB * HH * 2;  // 1024
    constexpr int PER = NBLK / 8;

    __shared__ ushort iB[2][128 * LDK];   // 20 KB

    const int tid = threadIdx.x;
    const int id  = blockIdx.x;
    const int orig = (id & 7) * PER + (id >> 3);
    const int row = orig >> 1, gy = orig & 1;
    const int b = row >> 7, y = row & 127;
    const int o0 = gy * 256;

    const int wave = tid >> 6, lane = tid & 63;
    const int wm = wave >> 2, wn = wave & 3;
    const int l31 = lane & 31, lhi = lane >> 5;
    const int spx = tid & 127;
    const int sko = __builtin_amdgcn_readfirstlane(tid >> 7);

    f32x16 acc[4] = {};
    ushort pb[8];

    auto FETCH4 = [&](int kc, int j0) {
        #pragma unroll
        for (int j = j0; j < j0 + 4; ++j) {
            const int k  = kc * 32 + sko * 8 + j;
            const int ic = k / 9;
            const int kk = k - ic * 9;
            const int ky = kk / 3;
            const int kx = kk - ky * 3;
            const int gyy = y + ky - 1;
            const int gx = spx + kx - 1;
            ushort u = 0;
            if ((unsigned)gyy < (unsigned)HH && (unsigned)gx < (unsigned)WW)
                u = inP[((size_t)b * 64 + ic) * HWSZ + gyy * WW + gx];
            pb[j] = u;
        }
    };
    auto WRITE = [&](int buf) {
        short8 pw;
        #pragma unroll
        for (int j = 0; j < 8; ++j) pw[j] = (short)pb[j];
        *(short8*)&iB[buf][spx * LDK + sko * 8] = pw;
    };

    FETCH4(0, 0); FETCH4(0, 4);
    WRITE(0);

    for (int kc = 0; kc < NCHUNK; ++kc) {
        __syncthreads();
        const int cur = kc & 1;
        const bool more = (kc + 1 < NCHUNK);

        #pragma unroll
        for (int ks = 0; ks < 2; ++ks) {
            // A fragments for this ks (issued before the B-prefetch half)
            half8 af[4];
            #pragma unroll
            for (int mg = 0; mg < 4; ++mg) {
                const size_t ga = (size_t)kc * 32 * OCPAD + (size_t)ks * 16 * OCPAD
                                + (o0 + wm * 128 + mg * 32 + l31) * 16 + lhi * 8;
                af[mg] = __builtin_bit_cast(half8, *(const short8*)&whiF[ga]);
            }
            if (more) FETCH4(kc + 1, ks * 4);

            const int koff = ks * 16 + lhi * 8;
            const int ib = (wn * 32 + l31) * LDK + koff;
            const half8 bh = __builtin_bit_cast(half8, *(const short8*)&iB[cur][ib]);
            #pragma unroll
            for (int mg = 0; mg < 4; ++mg)
                acc[mg] = __builtin_amdgcn_mfma_f32_32x32x16_f16(af[mg], bh, acc[mg], 0, 0, 0);
        }

        if (more) WRITE(1 - cur);
    }

    // ---- epilogue ----
    const int px = wn * 32 + l31;
    #pragma unroll
    for (int mg = 0; mg < 4; ++mg) {
        #pragma unroll
        for (int r = 0; r < 16; ++r) {
            const int oc = o0 + wm * 128 + mg * 32 + (r & 3) + 8 * (r >> 2) + 4 * lhi;
            if (oc < 432) {
                float v = acc[mg][r] + bias[oc];
                float res;
                if (oc < 288) {
                    const float fl = flow[(((size_t)b * 2 + ((oc & 1) ? 0 : 1)) * HH + y) * WW + px];
                    res = 10.f * tanhf(v) + fl;
                } else {
                    res = 1.f / (1.f + expf(-v));
                }
                outF[((size_t)b * 432 + oc) * HWSZ + y * WW + px] = res;
            }
        }
    }
}

// ---------------------------------------------------------------------------
// MFMA deformable conv (single-fp16 A). 256 threads = 4 waves.
// wm splits k9 range (0-4 / 5-8); LDS reduction at the end.
// ---------------------------------------------------------------------------
__global__ __launch_bounds__(256, 4) void deform_v7(
    const float4* __restrict__ xP, const float* __restrict__ offm,
    const ushort* __restrict__ wdfh,
    const float* __restrict__ bias, float* __restrict__ outp)
{
    __shared__ float red[2][64][34];

    const int tid = threadIdx.x;
    const int id  = blockIdx.x;
    const int orig = (id & 7) * 128 + (id >> 3);
    const int x0 = (orig & 1) * 64;
    const int rl = orig >> 1;
    const int y = rl & 127, b = rl >> 7;

    const int wave = tid >> 6, lane = tid & 63;
    const int wm = wave >> 1, wn = wave & 1;
    const int l31 = lane & 31, lhi = lane >> 5;

    const int xp  = x0 + wn * 32 + l31;
    const int pix = y * WW + xp;
    const float* offb = offm + (size_t)b * 432 * HWSZ;
    const float fy = (float)y, fx = (float)xp;

    f32x16 acc[2] = {};

    const int k9lo = wm ? 5 : 0;
    const int k9hi = wm ? 9 : 5;
    for (int k9 = k9lo; k9 < k9hi; ++k9) {
        const float kyf = (float)(k9 / 3 - 1);
        const float kxf = (float)(k9 % 3 - 1);
        #pragma unroll
        for (int hv = 0; hv < 2; ++hv) {
            #pragma unroll
            for (int ks = 0; ks < 2; ++ks) {
                short8 bfs;
                #pragma unroll
                for (int d2 = 0; d2 < 2; ++d2) {
                    const int dg = hv * 8 + ks * 4 + lhi * 2 + d2;
                    const float dy = offb[(size_t)(dg * 18 + k9 * 2)     * HWSZ + pix];
                    const float dx = offb[(size_t)(dg * 18 + k9 * 2 + 1) * HWSZ + pix];
                    const float mk = offb[(size_t)(288 + dg * 9 + k9)    * HWSZ + pix];
                    const float py = dy + kyf + fy;
                    const float px = dx + kxf + fx;
                    const float y0f = floorf(py), x0f = floorf(px);
                    const float ly = py - y0f, lx = px - x0f;
                    const int yi = (int)y0f, xi = (int)x0f;
                    const float w00 = (1.f - ly) * (1.f - lx), w01 = (1.f - ly) * lx;
                    const float w10 = ly * (1.f - lx),         w11 = ly * lx;
                    const bool vy0 = (unsigned)yi < (unsigned)HH, vy1 = (unsigned)(yi + 1) < (unsigned)HH;
                    const bool vx0 = (unsigned)xi < (unsigned)WW, vx1 = (unsigned)(xi + 1) < (unsigned)WW;
                    const float f00 = (vy0 && vx0) ? w00 * mk : 0.f;
                    const float f01 = (vy0 && vx1) ? w01 * mk : 0.f;
                    const float f10 = (vy1 && vx0) ? w10 * mk : 0.f;
                    const float f11 = (vy1 && vx1) ? w11 * mk : 0.f;
                    const int cy0 = min(max(yi, 0), HH - 1), cy1 = min(max(yi + 1, 0), HH - 1);
                    const int cx0 = min(max(xi, 0), WW - 1), cx1 = min(max(xi + 1, 0), WW - 1);
                    const float4* xg = xP + (size_t)(b * 16 + dg) * HWSZ;
                    const float4 c00 = xg[cy0 * WW + cx0], c01 = xg[cy0 * WW + cx1];
                    const float4 c10 = xg[cy1 * WW + cx0], c11 = xg[cy1 * WW + cx1];
                    bfs[d2 * 4 + 0] = (short)f16_rn(f00 * c00.x + f01 * c01.x + f10 * c10.x + f11 * c11.x);
                    bfs[d2 * 4 + 1] = (short)f16_rn(f00 * c00.y + f01 * c01.y + f10 * c10.y + f11 * c11.y);
                    bfs[d2 * 4 + 2] = (short)f16_rn(f00 * c00.z + f01 * c01.z + f10 * c10.z + f11 * c11.z);
                    bfs[d2 * 4 + 3] = (short)f16_rn(f00 * c00.w + f01 * c01.w + f10 * c10.w + f11 * c11.w);
                }
                const half8 bf = __builtin_bit_cast(half8, bfs);
                const size_t abase = (size_t)((k9 * 2 + hv) * 2 + ks) * 1024 + l31 * 16 + lhi * 8;
                #pragma unroll
                for (int mg = 0; mg < 2; ++mg) {
                    const half8 ah = __builtin_bit_cast(half8, *(const short8*)&wdfh[abase + mg * 512]);
                    acc[mg] = __builtin_amdgcn_mfma_f32_32x32x16_f16(ah, bf, acc[mg], 0, 0, 0);
                }
            }
        }
    }

    if (wm == 1) {
        #pragma unroll
        for (int mg = 0; mg < 2; ++mg)
            #pragma unroll
            for (int r = 0; r < 16; ++r)
                red[wn][lane][mg * 16 + r] = acc[mg][r];
    }
    __syncthreads();
    if (wm == 0) {
        #pragma unroll
        for (int mg = 0; mg < 2; ++mg)
            #pragma unroll
            for (int r = 0; r < 16; ++r) {
                const int oc = mg * 32 + (r & 3) + 8 * (r >> 2) + 4 * lhi;
                const float v = acc[mg][r] + red[wn][lane][mg * 16 + r] + bias[oc];
                outp[(((size_t)b * 64 + oc) * HH + y) * WW + xp] = v;
            }
    }
}

// ---------------------------------------------------------------------------
extern "C" void kernel_launch(void* const* d_in, const int* in_sizes, int n_in,
                              void* d_out, int out_size, void* d_ws, size_t ws_size,
                              hipStream_t stream) {
    const float* x    = (const float*)d_in[0];
    const float* xfw  = (const float*)d_in[1];
    const float* xcur = (const float*)d_in[2];
    const float* flow = (const float*)d_in[3];
    const float* w0   = (const float*)d_in[4];
    const float* b0   = (const float*)d_in[5];
    const float* w1   = (const float*)d_in[6];
    const float* b1   = (const float*)d_in[7];
    const float* w2   = (const float*)d_in[8];
    const float* b2   = (const float*)d_in[9];
    const float* w3   = (const float*)d_in[10];
    const float* b3   = (const float*)d_in[11];
    const float* wdcn = (const float*)d_in[12];
    const float* bdcn = (const float*)d_in[13];
    float* out = (float*)d_out;

    // workspace (aliased; stream order makes it safe):
    //   [0, 113.2MB) offm fp32 (concatP fp16 17.3MB aliases head, dead before conv3)
    //   h0P fp16 8.4MB (conv2 reuses = h2P) | h1P fp16 8.4MB |
    //   xP float4 16.8MB | single-plane fp16 weights ~1MB
    float* offm     = (float*)d_ws;
    ushort* concatP = (ushort*)d_ws;
    ushort* h0P     = (ushort*)((char*)d_ws + (size_t)BB * 432 * HWSZ * 4);
    ushort* h1P     = h0P + (size_t)BB * 64 * HWSZ;
    float4* xP      = (float4*)(h1P + (size_t)BB * 64 * HWSZ);
    ushort* wp      = (ushort*)(xP + (size_t)BB * 16 * HWSZ);
    ushort* wdh = wp;
    ushort* w0h = wdh + 64 * 576;
    ushort* w1h = w0h + 64 * 1184;
    ushort* w2h = w1h + 64 * 576;
    ushort* w3h = w2h + 64 * 576;          // 512*576
    ushort* h2P = h0P;                     // conv2 output reuses h0P

    prep_wf_k<<<dim3((64 * 1184 + 255) / 256), dim3(256), 0, stream>>>(w0, w0h, 64, 1170, 64, 1184);
    prep_wf_k<<<dim3((64 * 576 + 255) / 256),  dim3(256), 0, stream>>>(w1, w1h, 64, 576, 64, 576);
    prep_wf_k<<<dim3((64 * 576 + 255) / 256),  dim3(256), 0, stream>>>(w2, w2h, 64, 576, 64, 576);
    prep_wf_k<<<dim3((512 * 576 + 255) / 256), dim3(256), 0, stream>>>(w3, w3h, 432, 576, 512, 576);
    prep_wdf_k<<<dim3((64 * 576 + 255) / 256), dim3(256), 0, stream>>>(wdcn, wdh);
    cvt_in_k<<<dim3((BB * 132 * HWSZ + 255) / 256), dim3(256), 0, stream>>>(xfw, xcur, flow, concatP);

    conv_n256<132, 1184><<<dim3(BB * 64), dim3(512), 0, stream>>>(concatP, w0h, b0, h0P);
    conv_n256<64, 576><<<dim3(BB * 64), dim3(512), 0, stream>>>(h0P, w1h, b1, h1P);
    conv_n256<64, 576><<<dim3(BB * 64), dim3(512), 0, stream>>>(h1P, w2h, b2, h2P);
    pack_x_k<<<dim3((BB * 16 * HWSZ + 255) / 256), dim3(256), 0, stream>>>(x, xP);
    conv_m512<576><<<dim3(BB * HH * 2), dim3(512), 0, stream>>>(h2P, w3h, b3, offm, flow);

    deform_v7<<<dim3(1024), dim3(256), 0, stream>>>(xP, offm, wdh, bdcn, out);
}